// Round 1
// baseline (4112.321 us; speedup 1.0000x reference)
//
#include <hip/hip_runtime.h>

#define T_SEQ 2048
#define C_DIM 2048
#define NH    16
#define HD    128

// ===================== fp32 tiled GEMM: C[M,N] = A[M,K] @ B[K,N] =====================
// 128x128 tile, BK=8, 256 threads, 8x8 micro-tile as 2x2 quadrants of 4x4
// (quadrant layout keeps every ds_read_b128 on >=8 distinct banks -> <=2-way conflict = free)
__global__ __launch_bounds__(256) void sgemm128(
    const float* __restrict__ A, const float* __restrict__ B,
    float* __restrict__ C, int M, int N, int K)
{
    __shared__ float As[8][128];   // As[k][m] (A tile transposed)
    __shared__ float Bs[8][128];
    const int tid = threadIdx.x;
    const int tx = tid & 15, ty = tid >> 4;
    const int bm = blockIdx.y * 128, bn = blockIdx.x * 128;

    const int am = tid >> 1, ak = (tid & 1) * 4;
    const int br = tid >> 5, bc = (tid & 31) * 4;
    const float* Ap = A + (size_t)(bm + am) * K + ak;
    const float* Bp = B + (size_t)br * N + bn + bc;

    float4 aReg = *(const float4*)Ap;
    float4 bReg = *(const float4*)Bp;

    float acc[8][8];
#pragma unroll
    for (int i = 0; i < 8; ++i)
#pragma unroll
        for (int j = 0; j < 8; ++j) acc[i][j] = 0.f;

    for (int k0 = 0; k0 < K; k0 += 8) {
        __syncthreads();
        As[ak + 0][am] = aReg.x;
        As[ak + 1][am] = aReg.y;
        As[ak + 2][am] = aReg.z;
        As[ak + 3][am] = aReg.w;
        *(float4*)&Bs[br][bc] = bReg;
        __syncthreads();
        if (k0 + 8 < K) {   // prefetch next K-slab while computing current
            aReg = *(const float4*)(Ap + k0 + 8);
            bReg = *(const float4*)(Bp + (size_t)(k0 + 8) * N);
        }
#pragma unroll
        for (int kk = 0; kk < 8; ++kk) {
            float a[8], b[8];
            *(float4*)&a[0] = *(const float4*)&As[kk][ty * 4];
            *(float4*)&a[4] = *(const float4*)&As[kk][64 + ty * 4];
            *(float4*)&b[0] = *(const float4*)&Bs[kk][tx * 4];
            *(float4*)&b[4] = *(const float4*)&Bs[kk][64 + tx * 4];
#pragma unroll
            for (int i = 0; i < 8; ++i)
#pragma unroll
                for (int j = 0; j < 8; ++j)
                    acc[i][j] = fmaf(a[i], b[j], acc[i][j]);
        }
    }

#pragma unroll
    for (int iq = 0; iq < 2; ++iq)
#pragma unroll
        for (int r = 0; r < 4; ++r) {
            size_t row = (size_t)(bm + iq * 64 + ty * 4 + r);
            float* cp = C + row * N + bn;
            *(float4*)&cp[tx * 4] =
                make_float4(acc[iq*4+r][0], acc[iq*4+r][1], acc[iq*4+r][2], acc[iq*4+r][3]);
            *(float4*)&cp[64 + tx * 4] =
                make_float4(acc[iq*4+r][4], acc[iq*4+r][5], acc[iq*4+r][6], acc[iq*4+r][7]);
        }
}

// ===================== conv3(causal,depthwise) + rmsnorm + rope + transpose =====================
// one block = one (b, t, h); 128 threads = one d each; handles all 4 streams (q,k,v,intent)
__global__ __launch_bounds__(128) void conv_norm_rope(
    const float* __restrict__ qkv,
    const float* __restrict__ wq, const float* __restrict__ wk,
    const float* __restrict__ wv, const float* __restrict__ wi,
    const float* __restrict__ qnw, const float* __restrict__ knw,
    const float* __restrict__ cosT, const float* __restrict__ sinT,
    float* __restrict__ qt, float* __restrict__ kt,
    float* __restrict__ vt, float* __restrict__ it)
{
    const int t = blockIdx.x, h = blockIdx.y, b = blockIdx.z;
    const int d = threadIdx.x;
    const int c = h * HD + d;
    const size_t rowbase = ((size_t)(b * T_SEQ + t)) * (4 * C_DIM);

    const float* Wt[4] = { wq, wk, wv, wi };
    float z[4];
#pragma unroll
    for (int s = 0; s < 4; ++s) {
        const float* w = Wt[s] + c * 3;
        float w0 = w[0], w1 = w[1], w2 = w[2];
        size_t idx = rowbase + (size_t)s * C_DIM + c;
        float x0 = qkv[idx];
        float x1 = (t >= 1) ? qkv[idx - (size_t)4 * C_DIM] : 0.f;
        float x2 = (t >= 2) ? qkv[idx - (size_t)8 * C_DIM] : 0.f;
        z[s] = fmaf(w0, x2, fmaf(w1, x1, w2 * x0));
    }

    // block rmsnorm stats for q (z[0]) and k (z[1]) over 128 lanes (2 waves)
    float sq = z[0] * z[0], sk = z[1] * z[1];
#pragma unroll
    for (int off = 32; off > 0; off >>= 1) {
        sq += __shfl_down(sq, off);
        sk += __shfl_down(sk, off);
    }
    __shared__ float red[4];
    const int wid = threadIdx.x >> 6, lane = threadIdx.x & 63;
    if (lane == 0) { red[wid * 2 + 0] = sq; red[wid * 2 + 1] = sk; }
    __syncthreads();
    const float rq = rsqrtf((red[0] + red[2]) * (1.f / HD) + 1e-5f);
    const float rk = rsqrtf((red[1] + red[3]) * (1.f / HD) + 1e-5f);

    float zq = z[0] * rq * qnw[d];
    float zk = z[1] * rk * knw[d];
    // rope: partner lane is d^1 (same wave since wave=64)
    float pq = __shfl_xor(zq, 1);
    float pk = __shfl_xor(zk, 1);
    float cv = cosT[t * (HD / 2) + (d >> 1)];
    float sv = sinT[t * (HD / 2) + (d >> 1)];
    float oq = (d & 1) ? (pq * sv + zq * cv) : (zq * cv - pq * sv);
    float ok = (d & 1) ? (pk * sv + zk * cv) : (zk * cv - pk * sv);

    size_t o = ((size_t)(b * NH + h) * T_SEQ + t) * HD + d;
    qt[o] = oq; kt[o] = ok; vt[o] = z[2]; it[o] = z[3];
}

// ===================== causal flash attention (fp32) + sigmoid(intent) gate =====================
// block: 256 threads, BQ=64 rows, BK=64 keys per tile, online softmax.
// tx = tid&15 (cols), ty = tid>>4 (16 row-groups); scores micro-tile 4x4 at
// (i = r*16+ty, j = c*16+tx)  -> all LDS reads land on >=4 distinct banks (pad 132 / 66).
#define QSTR 132
#define PSTR 66
__global__ __launch_bounds__(256) void flash_attn(
    const float* __restrict__ qt, const float* __restrict__ kt,
    const float* __restrict__ vt, const float* __restrict__ it,
    float* __restrict__ y)
{
    extern __shared__ float sm[];
    float* Qs = sm;                 // 64*132
    float* Ks = Qs + 64 * QSTR;     // 64*132
    float* Vs = Ks + 64 * QSTR;     // 64*132
    float* Ps = Vs + 64 * QSTR;     // 64*66  (stored transposed: Ps[j][i])

    const int tid = threadIdx.x;
    const int tx = tid & 15, ty = tid >> 4;
    const int qtile = gridDim.x - 1 - blockIdx.x;   // heaviest tiles first
    const int bh = blockIdx.y;
    const int b = bh >> 4, h = bh & 15;
    const int q0 = qtile * 64;

    // load Q tile
    const float* qb = qt + ((size_t)bh * T_SEQ + q0) * HD;
#pragma unroll
    for (int cch = 0; cch < 8; ++cch) {
        int fi = cch * 256 + tid;
        int row = fi >> 5, col = (fi & 31) * 4;
        *(float4*)&Qs[row * QSTR + col] = *(const float4*)(qb + row * HD + col);
    }

    float o[4][8];
    float m[4], l[4];
#pragma unroll
    for (int r = 0; r < 4; ++r) {
        m[r] = -1e30f; l[r] = 0.f;
#pragma unroll
        for (int j = 0; j < 8; ++j) o[r][j] = 0.f;
    }
    const float scale = 0.08838834764831845f;  // 1/sqrt(128)

    for (int kti = 0; kti <= qtile; ++kti) {
        const int k0 = kti * 64;
        const float* kb = kt + ((size_t)bh * T_SEQ + k0) * HD;
        const float* vb = vt + ((size_t)bh * T_SEQ + k0) * HD;
        float4 kreg[8], vreg[8];
#pragma unroll
        for (int cch = 0; cch < 8; ++cch) {
            int fi = cch * 256 + tid;
            int row = fi >> 5, col = (fi & 31) * 4;
            kreg[cch] = *(const float4*)(kb + row * HD + col);
            vreg[cch] = *(const float4*)(vb + row * HD + col);
        }
        __syncthreads();   // prev PV done (and Qs ready on first iter)
#pragma unroll
        for (int cch = 0; cch < 8; ++cch) {
            int fi = cch * 256 + tid;
            int row = fi >> 5, col = (fi & 31) * 4;
            *(float4*)&Ks[row * QSTR + col] = kreg[cch];
            *(float4*)&Vs[row * QSTR + col] = vreg[cch];
        }
        __syncthreads();

        // ---- scores: s[r][c] = q(i) . k(j) ----
        float s[4][4];
#pragma unroll
        for (int r = 0; r < 4; ++r)
#pragma unroll
            for (int c2 = 0; c2 < 4; ++c2) s[r][c2] = 0.f;

#pragma unroll 4
        for (int d0 = 0; d0 < HD; d0 += 4) {
            float4 qv[4], kv[4];
#pragma unroll
            for (int r = 0; r < 4; ++r)
                qv[r] = *(const float4*)&Qs[(r * 16 + ty) * QSTR + d0];
#pragma unroll
            for (int c2 = 0; c2 < 4; ++c2)
                kv[c2] = *(const float4*)&Ks[(c2 * 16 + tx) * QSTR + d0];
#pragma unroll
            for (int r = 0; r < 4; ++r)
#pragma unroll
                for (int c2 = 0; c2 < 4; ++c2) {
                    s[r][c2] = fmaf(qv[r].x, kv[c2].x, s[r][c2]);
                    s[r][c2] = fmaf(qv[r].y, kv[c2].y, s[r][c2]);
                    s[r][c2] = fmaf(qv[r].z, kv[c2].z, s[r][c2]);
                    s[r][c2] = fmaf(qv[r].w, kv[c2].w, s[r][c2]);
                }
        }

        // ---- online softmax ----
        const bool diag = (kti == qtile);
#pragma unroll
        for (int r = 0; r < 4; ++r) {
            const int qi = q0 + r * 16 + ty;
            float mx = -1e30f;
#pragma unroll
            for (int c2 = 0; c2 < 4; ++c2) {
                float v = s[r][c2] * scale;
                if (diag && (k0 + c2 * 16 + tx) > qi) v = -1e30f;
                s[r][c2] = v;
                mx = fmaxf(mx, v);
            }
            mx = fmaxf(mx, __shfl_xor(mx, 1));
            mx = fmaxf(mx, __shfl_xor(mx, 2));
            mx = fmaxf(mx, __shfl_xor(mx, 4));
            mx = fmaxf(mx, __shfl_xor(mx, 8));
            const float mn = fmaxf(m[r], mx);
            const float corr = __expf(m[r] - mn);
            m[r] = mn;
            float ps = 0.f;
#pragma unroll
            for (int c2 = 0; c2 < 4; ++c2) {
                float p = __expf(s[r][c2] - mn);
                s[r][c2] = p;
                ps += p;
            }
            ps += __shfl_xor(ps, 1);
            ps += __shfl_xor(ps, 2);
            ps += __shfl_xor(ps, 4);
            ps += __shfl_xor(ps, 8);
            l[r] = l[r] * corr + ps;
#pragma unroll
            for (int j = 0; j < 8; ++j) o[r][j] *= corr;
        }

        // ---- stage P transposed: Ps[j][i] ----
#pragma unroll
        for (int r = 0; r < 4; ++r)
#pragma unroll
            for (int c2 = 0; c2 < 4; ++c2)
                Ps[(c2 * 16 + tx) * PSTR + (r * 16 + ty)] = s[r][c2];
        __syncthreads();

        // ---- PV: o[i][d] += sum_j P[i][j] * V[j][d];  d = tx*4 (+64) ----
#pragma unroll 2
        for (int j = 0; j < 64; ++j) {
            float4 v0 = *(const float4*)&Vs[j * QSTR + tx * 4];
            float4 v1 = *(const float4*)&Vs[j * QSTR + 64 + tx * 4];
#pragma unroll
            for (int r = 0; r < 4; ++r) {
                float p = Ps[j * PSTR + r * 16 + ty];
                o[r][0] = fmaf(p, v0.x, o[r][0]);
                o[r][1] = fmaf(p, v0.y, o[r][1]);
                o[r][2] = fmaf(p, v0.z, o[r][2]);
                o[r][3] = fmaf(p, v0.w, o[r][3]);
                o[r][4] = fmaf(p, v1.x, o[r][4]);
                o[r][5] = fmaf(p, v1.y, o[r][5]);
                o[r][6] = fmaf(p, v1.z, o[r][6]);
                o[r][7] = fmaf(p, v1.w, o[r][7]);
            }
        }
    }

    // ---- epilogue: normalize, sigmoid(intent) gate, store to y[b,t,h*128+d] ----
#pragma unroll
    for (int r = 0; r < 4; ++r) {
        const float inv = 1.f / l[r];
        const int tq = q0 + r * 16 + ty;
        const float* ip = it + ((size_t)bh * T_SEQ + tq) * HD;
        float4 g0 = *(const float4*)(ip + tx * 4);
        float4 g1 = *(const float4*)(ip + 64 + tx * 4);
        float* yp = y + ((size_t)(b * T_SEQ + tq)) * C_DIM + h * HD;
        float4 r0, r1;
        r0.x = o[r][0] * inv * (1.f / (1.f + __expf(-g0.x)));
        r0.y = o[r][1] * inv * (1.f / (1.f + __expf(-g0.y)));
        r0.z = o[r][2] * inv * (1.f / (1.f + __expf(-g0.z)));
        r0.w = o[r][3] * inv * (1.f / (1.f + __expf(-g0.w)));
        r1.x = o[r][4] * inv * (1.f / (1.f + __expf(-g1.x)));
        r1.y = o[r][5] * inv * (1.f / (1.f + __expf(-g1.y)));
        r1.z = o[r][6] * inv * (1.f / (1.f + __expf(-g1.z)));
        r1.w = o[r][7] * inv * (1.f / (1.f + __expf(-g1.w)));
        *(float4*)&yp[tx * 4] = r0;
        *(float4*)&yp[64 + tx * 4] = r1;
    }
}

// ===================== launch =====================
extern "C" void kernel_launch(void* const* d_in, const int* in_sizes, int n_in,
                              void* d_out, int out_size, void* d_ws, size_t ws_size,
                              hipStream_t stream)
{
    const float* x     = (const float*)d_in[0];
    const float* cosT  = (const float*)d_in[1];
    const float* sinT  = (const float*)d_in[2];
    const float* Wqkv  = (const float*)d_in[3];
    const float* wq    = (const float*)d_in[4];
    const float* wk    = (const float*)d_in[5];
    const float* wv    = (const float*)d_in[6];
    const float* wi    = (const float*)d_in[7];
    const float* qnw   = (const float*)d_in[8];
    const float* knw   = (const float*)d_in[9];
    const float* Wproj = (const float*)d_in[10];
    float* out = (float*)d_out;

    // workspace layout (fp32): qkv[2*2048*8192] | qt,kt,vt,it [2*16*2048*128 each]
    // total = 256 MiB; y reuses qkv region after stage B.
    float* qkv = (float*)d_ws;
    float* qt  = qkv + (size_t)2 * T_SEQ * 4 * C_DIM;
    float* ktp = qt  + (size_t)2 * NH * T_SEQ * HD;
    float* vtp = ktp + (size_t)2 * NH * T_SEQ * HD;
    float* itp = vtp + (size_t)2 * NH * T_SEQ * HD;
    float* y   = qkv;   // qkv dead after conv_norm_rope

    // A: qkv = x @ Wqkv   (M=4096, N=8192, K=2048)
    sgemm128<<<dim3(8192 / 128, 4096 / 128), 256, 0, stream>>>(x, Wqkv, qkv, 4096, 8192, 2048);
    // B: conv + rmsnorm + rope + transpose to (B,H,T,hd)
    conv_norm_rope<<<dim3(T_SEQ, NH, 2), 128, 0, stream>>>(
        qkv, wq, wk, wv, wi, qnw, knw, cosT, sinT, qt, ktp, vtp, itp);
    // C: causal flash attention + sigmoid gate -> y (B,T,C)
    size_t smem = (size_t)(3 * 64 * QSTR + 64 * PSTR) * sizeof(float);
    flash_attn<<<dim3(T_SEQ / 64, 2 * NH), 256, smem, stream>>>(qt, ktp, vtp, itp, y);
    // D: out = y @ Wproj  (M=4096, N=2048, K=2048)
    sgemm128<<<dim3(2048 / 128, 4096 / 128), 256, 0, stream>>>(y, Wproj, out, 4096, 2048, 2048);
}

// Round 2
// 2450.933 us; speedup vs baseline: 1.6779x; 1.6779x over previous
//
#include <hip/hip_runtime.h>
#include <stdint.h>

#define T_SEQ 2048
#define C_DIM 2048
#define NH    16
#define HD    128

typedef __attribute__((ext_vector_type(8))) short short8;
typedef __attribute__((ext_vector_type(4))) float f32x4;

__device__ __forceinline__ short f2bf(float f) {
    uint32_t x = __float_as_uint(f);
    uint32_t r = (x + 0x7fffu + ((x >> 16) & 1u)) >> 16;   // RNE
    return (short)r;
}
__device__ __forceinline__ float bf2f(short s) {
    return __uint_as_float(((uint32_t)(unsigned short)s) << 16);
}

// ============ prep A-side: fp32 [M][K] -> tiled bf16 [mblk][kb][128][32] (hi | optional lo) ============
__global__ __launch_bounds__(256) void prep_a(
    const float* __restrict__ X, short* __restrict__ Apk, int K, int split)
{
    const int kb = blockIdx.x, mblk = blockIdx.y, tid = threadIdx.x;
    const int kpb = K / 32;
    const int nkb = kpb << split;
    const int r0 = tid >> 3, c0 = (tid & 7) * 4;
    const size_t hiBase = ((size_t)mblk * nkb + kb) * 4096;
    const size_t loBase = hiBase + (size_t)kpb * 4096;
#pragma unroll
    for (int it = 0; it < 4; ++it) {
        const int row = it * 32 + r0;
        const float4 v = *(const float4*)&X[(size_t)(mblk * 128 + row) * K + kb * 32 + c0];
        float f[4] = { v.x, v.y, v.z, v.w };
        short h[4];
#pragma unroll
        for (int j = 0; j < 4; ++j) h[j] = f2bf(f[j]);
        *(int2*)&Apk[hiBase + row * 32 + c0] =
            make_int2((h[0] & 0xffff) | (h[1] << 16), (h[2] & 0xffff) | (h[3] << 16));
        if (split) {
            short l[4];
#pragma unroll
            for (int j = 0; j < 4; ++j) l[j] = f2bf(f[j] - bf2f(h[j]));
            *(int2*)&Apk[loBase + row * 32 + c0] =
                make_int2((l[0] & 0xffff) | (l[1] << 16), (l[2] & 0xffff) | (l[3] << 16));
        }
    }
}

// ============ prep B-side: fp32 [K][N] -> transposed tiled bf16 [nblk][kb][128n][32k] ============
__global__ __launch_bounds__(256) void prep_b(
    const float* __restrict__ W, short* __restrict__ Bpk, int K, int N, int split)
{
    const int kb = blockIdx.x, nblk = blockIdx.y, tid = threadIdx.x;
    const int kpb = K / 32;
    const int nkb = kpb << split;
    __shared__ float Ws[32][129];
    {
        const int r = tid >> 3, cbase = (tid & 7) * 4;
#pragma unroll
        for (int itc = 0; itc < 4; ++itc) {
            const int c = cbase + itc * 32;
            const float4 v = *(const float4*)&W[(size_t)(kb * 32 + r) * N + nblk * 128 + c];
            Ws[r][c] = v.x; Ws[r][c + 1] = v.y; Ws[r][c + 2] = v.z; Ws[r][c + 3] = v.w;
        }
    }
    __syncthreads();
    const int n = tid >> 1, ks = (tid & 1) * 16;
    const size_t hiBase = ((size_t)nblk * nkb + kb) * 4096;
    float f[16];
#pragma unroll
    for (int j = 0; j < 16; ++j) f[j] = Ws[ks + j][n];   // stride 129 -> conflict-free
    int hw[8];
#pragma unroll
    for (int j = 0; j < 8; ++j) {
        short a = f2bf(f[2 * j]), b = f2bf(f[2 * j + 1]);
        hw[j] = (a & 0xffff) | (b << 16);
    }
    *(int4*)&Bpk[hiBase + n * 32 + ks]     = make_int4(hw[0], hw[1], hw[2], hw[3]);
    *(int4*)&Bpk[hiBase + n * 32 + ks + 8] = make_int4(hw[4], hw[5], hw[6], hw[7]);
    if (split) {
        const size_t loBase = hiBase + (size_t)kpb * 4096;
        int lw[8];
#pragma unroll
        for (int j = 0; j < 8; ++j) {
            short ah = f2bf(f[2 * j]);     float ra = f[2 * j]     - bf2f(ah);
            short bh = f2bf(f[2 * j + 1]); float rb = f[2 * j + 1] - bf2f(bh);
            short a = f2bf(ra), b = f2bf(rb);
            lw[j] = (a & 0xffff) | (b << 16);
        }
        *(int4*)&Bpk[loBase + n * 32 + ks]     = make_int4(lw[0], lw[1], lw[2], lw[3]);
        *(int4*)&Bpk[loBase + n * 32 + ks + 8] = make_int4(lw[4], lw[5], lw[6], lw[7]);
    }
}

// ============ bf16 MFMA GEMM: C[M,N] fp32 = A' @ B'  (m97-style 128x128 tile, BK=32) ============
// A/B fragments: lane holds dim=(lane&15), k=(lane>>4)*8+[0..7]  (16x16x32 layout)
// C/D: col=lane&15, row=(lane>>4)*4+reg  [measured m89]
// split=1: virtual kb in [0,192) -> (Ahi@Bhi | Ahi@Blo | Alo@Bhi), hi/lo tiles stacked along kb.
__global__ __launch_bounds__(256) void gemm_bf16(
    const short* __restrict__ Apk, const short* __restrict__ Bpk,
    float* __restrict__ C, int N, int nkbA, int nkbB, int nkb, int split)
{
    __shared__ short As[4096];   // [128 rows][32 k] bf16 = 8 KB
    __shared__ short Bs[4096];   // [128 n][32 k]
    const int tid = threadIdx.x;
    const int lane = tid & 63, w = tid >> 6;
    const int wr = w >> 1, wc = w & 1;                 // 2x2 waves, 64x64 each
    const int bm = blockIdx.y * 128, bn = blockIdx.x * 128;
    const size_t Abase = (size_t)blockIdx.y * nkbA * 4096;
    const size_t Bbase = (size_t)blockIdx.x * nkbB * 4096;
    const int r16 = lane & 15, q8 = (lane >> 4) * 8;

    const f32x4 zero = { 0.f, 0.f, 0.f, 0.f };
    f32x4 acc[4][4];
#pragma unroll
    for (int m = 0; m < 4; ++m)
#pragma unroll
        for (int n = 0; n < 4; ++n) acc[m][n] = zero;

    float4 ra[2], rb[2];
    {
        const short* ga = Apk + Abase;
        const short* gb = Bpk + Bbase;
#pragma unroll
        for (int i = 0; i < 2; ++i) {
            ra[i] = *(const float4*)(ga + i * 2048 + tid * 8);
            rb[i] = *(const float4*)(gb + i * 2048 + tid * 8);
        }
    }
    for (int vkb = 0; vkb < nkb; ++vkb) {
        __syncthreads();
#pragma unroll
        for (int i = 0; i < 2; ++i) {
            *(float4*)&As[i * 2048 + tid * 8] = ra[i];
            *(float4*)&Bs[i * 2048 + tid * 8] = rb[i];
        }
        __syncthreads();
        if (vkb + 1 < nkb) {      // prefetch next tile into regs, overlaps MFMA below
            const int nv = vkb + 1;
            int akb, bkb;
            if (split) { akb = (nv < 64) ? nv : nv - 64; bkb = (nv < 128) ? nv : nv - 128; }
            else       { akb = nv; bkb = nv; }
            const short* ga = Apk + Abase + (size_t)akb * 4096;
            const short* gb = Bpk + Bbase + (size_t)bkb * 4096;
#pragma unroll
            for (int i = 0; i < 2; ++i) {
                ra[i] = *(const float4*)(ga + i * 2048 + tid * 8);
                rb[i] = *(const float4*)(gb + i * 2048 + tid * 8);
            }
        }
        short8 af[4], bfr[4];
#pragma unroll
        for (int m = 0; m < 4; ++m)
            af[m] = *(const short8*)&As[(wr * 64 + m * 16 + r16) * 32 + q8];
#pragma unroll
        for (int n = 0; n < 4; ++n)
            bfr[n] = *(const short8*)&Bs[(wc * 64 + n * 16 + r16) * 32 + q8];
#pragma unroll
        for (int m = 0; m < 4; ++m)
#pragma unroll
            for (int n = 0; n < 4; ++n)
                acc[m][n] = __builtin_amdgcn_mfma_f32_16x16x32_bf16(af[m], bfr[n], acc[m][n], 0, 0, 0);
    }
    const int rq = lane >> 4;
#pragma unroll
    for (int m = 0; m < 4; ++m)
#pragma unroll
        for (int n = 0; n < 4; ++n) {
            const int col = bn + wc * 64 + n * 16 + r16;
#pragma unroll
            for (int j = 0; j < 4; ++j) {
                const int row = bm + wr * 64 + m * 16 + rq * 4 + j;
                C[(size_t)row * N + col] = acc[m][n][j];
            }
        }
}

// ===================== conv3(causal,depthwise) + rmsnorm + rope + transpose =====================
__global__ __launch_bounds__(128) void conv_norm_rope(
    const float* __restrict__ qkv,
    const float* __restrict__ wq, const float* __restrict__ wk,
    const float* __restrict__ wv, const float* __restrict__ wi,
    const float* __restrict__ qnw, const float* __restrict__ knw,
    const float* __restrict__ cosT, const float* __restrict__ sinT,
    float* __restrict__ qt, float* __restrict__ kt,
    float* __restrict__ vt, float* __restrict__ it)
{
    const int t = blockIdx.x, h = blockIdx.y, b = blockIdx.z;
    const int d = threadIdx.x;
    const int c = h * HD + d;
    const size_t rowbase = ((size_t)(b * T_SEQ + t)) * (4 * C_DIM);

    const float* Wt[4] = { wq, wk, wv, wi };
    float z[4];
#pragma unroll
    for (int s = 0; s < 4; ++s) {
        const float* w = Wt[s] + c * 3;
        float w0 = w[0], w1 = w[1], w2 = w[2];
        size_t idx = rowbase + (size_t)s * C_DIM + c;
        float x0 = qkv[idx];
        float x1 = (t >= 1) ? qkv[idx - (size_t)4 * C_DIM] : 0.f;
        float x2 = (t >= 2) ? qkv[idx - (size_t)8 * C_DIM] : 0.f;
        z[s] = fmaf(w0, x2, fmaf(w1, x1, w2 * x0));
    }

    float sq = z[0] * z[0], sk = z[1] * z[1];
#pragma unroll
    for (int off = 32; off > 0; off >>= 1) {
        sq += __shfl_down(sq, off);
        sk += __shfl_down(sk, off);
    }
    __shared__ float red[4];
    const int wid = threadIdx.x >> 6, lane = threadIdx.x & 63;
    if (lane == 0) { red[wid * 2 + 0] = sq; red[wid * 2 + 1] = sk; }
    __syncthreads();
    const float rq = rsqrtf((red[0] + red[2]) * (1.f / HD) + 1e-5f);
    const float rk = rsqrtf((red[1] + red[3]) * (1.f / HD) + 1e-5f);

    float zq = z[0] * rq * qnw[d];
    float zk = z[1] * rk * knw[d];
    float pq = __shfl_xor(zq, 1);
    float pk = __shfl_xor(zk, 1);
    float cv = cosT[t * (HD / 2) + (d >> 1)];
    float sv = sinT[t * (HD / 2) + (d >> 1)];
    float oq = (d & 1) ? (pq * sv + zq * cv) : (zq * cv - pq * sv);
    float ok = (d & 1) ? (pk * sv + zk * cv) : (zk * cv - pk * sv);

    size_t o = ((size_t)(b * NH + h) * T_SEQ + t) * HD + d;
    qt[o] = oq; kt[o] = ok; vt[o] = z[2]; it[o] = z[3];
}

// ===================== causal flash attention (fp32, BQ=64, BK=32) + sigmoid gate =====================
// LDS 74.25 KB -> 2 blocks/CU (vs 118 KB / 1 block in round 1): 2 waves/SIMD for latency hiding.
#define QSTR 132
#define PSTR 66
__global__ __launch_bounds__(256) void flash_attn(
    const float* __restrict__ qt, const float* __restrict__ kt,
    const float* __restrict__ vt, const float* __restrict__ it,
    float* __restrict__ y)
{
    extern __shared__ float sm[];
    float* Qs = sm;                 // 64*132
    float* Ks = Qs + 64 * QSTR;     // 32*132
    float* Vs = Ks + 32 * QSTR;     // 32*132
    float* Ps = Vs + 32 * QSTR;     // 32*66  (transposed: Ps[j][i])

    const int tid = threadIdx.x;
    const int tx = tid & 15, ty = tid >> 4;
    const int qtile = gridDim.x - 1 - blockIdx.x;   // heaviest tiles first
    const int bh = blockIdx.y;
    const int b = bh >> 4, h = bh & 15;
    const int q0 = qtile * 64;

    const float* qb = qt + ((size_t)bh * T_SEQ + q0) * HD;
#pragma unroll
    for (int cch = 0; cch < 8; ++cch) {
        int fi = cch * 256 + tid;
        int row = fi >> 5, col = (fi & 31) * 4;
        *(float4*)&Qs[row * QSTR + col] = *(const float4*)(qb + row * HD + col);
    }

    float o[4][8];
    float m[4], l[4];
#pragma unroll
    for (int r = 0; r < 4; ++r) {
        m[r] = -1e30f; l[r] = 0.f;
#pragma unroll
        for (int j = 0; j < 8; ++j) o[r][j] = 0.f;
    }
    const float scale = 0.08838834764831845f;

    const int nkt = 2 * (qtile + 1);
    for (int kti = 0; kti < nkt; ++kti) {
        const int k0 = kti * 32;
        const float* kb = kt + ((size_t)bh * T_SEQ + k0) * HD;
        const float* vb = vt + ((size_t)bh * T_SEQ + k0) * HD;
        float4 kreg[4], vreg[4];
#pragma unroll
        for (int cch = 0; cch < 4; ++cch) {
            int fi = cch * 256 + tid;
            int row = fi >> 5, col = (fi & 31) * 4;
            kreg[cch] = *(const float4*)(kb + row * HD + col);
            vreg[cch] = *(const float4*)(vb + row * HD + col);
        }
        __syncthreads();
#pragma unroll
        for (int cch = 0; cch < 4; ++cch) {
            int fi = cch * 256 + tid;
            int row = fi >> 5, col = (fi & 31) * 4;
            *(float4*)&Ks[row * QSTR + col] = kreg[cch];
            *(float4*)&Vs[row * QSTR + col] = vreg[cch];
        }
        __syncthreads();

        float s[4][2];
#pragma unroll
        for (int r = 0; r < 4; ++r) { s[r][0] = 0.f; s[r][1] = 0.f; }

#pragma unroll 4
        for (int d0 = 0; d0 < HD; d0 += 4) {
            float4 qv[4], kv[2];
#pragma unroll
            for (int r = 0; r < 4; ++r)
                qv[r] = *(const float4*)&Qs[(r * 16 + ty) * QSTR + d0];
#pragma unroll
            for (int c2 = 0; c2 < 2; ++c2)
                kv[c2] = *(const float4*)&Ks[(c2 * 16 + tx) * QSTR + d0];
#pragma unroll
            for (int r = 0; r < 4; ++r)
#pragma unroll
                for (int c2 = 0; c2 < 2; ++c2) {
                    s[r][c2] = fmaf(qv[r].x, kv[c2].x, s[r][c2]);
                    s[r][c2] = fmaf(qv[r].y, kv[c2].y, s[r][c2]);
                    s[r][c2] = fmaf(qv[r].z, kv[c2].z, s[r][c2]);
                    s[r][c2] = fmaf(qv[r].w, kv[c2].w, s[r][c2]);
                }
        }

        const bool diag = (kti >= 2 * qtile);
#pragma unroll
        for (int r = 0; r < 4; ++r) {
            const int qi = q0 + r * 16 + ty;
            float mx = -1e30f;
#pragma unroll
            for (int c2 = 0; c2 < 2; ++c2) {
                float v = s[r][c2] * scale;
                if (diag && (k0 + c2 * 16 + tx) > qi) v = -1e30f;
                s[r][c2] = v;
                mx = fmaxf(mx, v);
            }
            mx = fmaxf(mx, __shfl_xor(mx, 1));
            mx = fmaxf(mx, __shfl_xor(mx, 2));
            mx = fmaxf(mx, __shfl_xor(mx, 4));
            mx = fmaxf(mx, __shfl_xor(mx, 8));
            const float mn = fmaxf(m[r], mx);
            const float corr = __expf(m[r] - mn);
            m[r] = mn;
            float ps = 0.f;
#pragma unroll
            for (int c2 = 0; c2 < 2; ++c2) {
                float p = __expf(s[r][c2] - mn);
                s[r][c2] = p;
                ps += p;
            }
            ps += __shfl_xor(ps, 1);
            ps += __shfl_xor(ps, 2);
            ps += __shfl_xor(ps, 4);
            ps += __shfl_xor(ps, 8);
            l[r] = l[r] * corr + ps;
#pragma unroll
            for (int j = 0; j < 8; ++j) o[r][j] *= corr;
        }

#pragma unroll
        for (int r = 0; r < 4; ++r)
#pragma unroll
            for (int c2 = 0; c2 < 2; ++c2)
                Ps[(c2 * 16 + tx) * PSTR + (r * 16 + ty)] = s[r][c2];
        __syncthreads();

#pragma unroll 2
        for (int j = 0; j < 32; ++j) {
            float4 v0 = *(const float4*)&Vs[j * QSTR + tx * 4];
            float4 v1 = *(const float4*)&Vs[j * QSTR + 64 + tx * 4];
#pragma unroll
            for (int r = 0; r < 4; ++r) {
                float p = Ps[j * PSTR + r * 16 + ty];
                o[r][0] = fmaf(p, v0.x, o[r][0]);
                o[r][1] = fmaf(p, v0.y, o[r][1]);
                o[r][2] = fmaf(p, v0.z, o[r][2]);
                o[r][3] = fmaf(p, v0.w, o[r][3]);
                o[r][4] = fmaf(p, v1.x, o[r][4]);
                o[r][5] = fmaf(p, v1.y, o[r][5]);
                o[r][6] = fmaf(p, v1.z, o[r][6]);
                o[r][7] = fmaf(p, v1.w, o[r][7]);
            }
        }
    }

#pragma unroll
    for (int r = 0; r < 4; ++r) {
        const float inv = 1.f / l[r];
        const int tq = q0 + r * 16 + ty;
        const float* ip = it + ((size_t)bh * T_SEQ + tq) * HD;
        float4 g0 = *(const float4*)(ip + tx * 4);
        float4 g1 = *(const float4*)(ip + 64 + tx * 4);
        float* yp = y + ((size_t)(b * T_SEQ + tq)) * C_DIM + h * HD;
        float4 r0, r1;
        r0.x = o[r][0] * inv * (1.f / (1.f + __expf(-g0.x)));
        r0.y = o[r][1] * inv * (1.f / (1.f + __expf(-g0.y)));
        r0.z = o[r][2] * inv * (1.f / (1.f + __expf(-g0.z)));
        r0.w = o[r][3] * inv * (1.f / (1.f + __expf(-g0.w)));
        r1.x = o[r][4] * inv * (1.f / (1.f + __expf(-g1.x)));
        r1.y = o[r][5] * inv * (1.f / (1.f + __expf(-g1.y)));
        r1.z = o[r][6] * inv * (1.f / (1.f + __expf(-g1.z)));
        r1.w = o[r][7] * inv * (1.f / (1.f + __expf(-g1.w)));
        *(float4*)&yp[tx * 4] = r0;
        *(float4*)&yp[64 + tx * 4] = r1;
    }
}

// ===================== launch =====================
extern "C" void kernel_launch(void* const* d_in, const int* in_sizes, int n_in,
                              void* d_out, int out_size, void* d_ws, size_t ws_size,
                              hipStream_t stream)
{
    const float* x     = (const float*)d_in[0];
    const float* cosT  = (const float*)d_in[1];
    const float* sinT  = (const float*)d_in[2];
    const float* Wqkv  = (const float*)d_in[3];
    const float* wq    = (const float*)d_in[4];
    const float* wk    = (const float*)d_in[5];
    const float* wv    = (const float*)d_in[6];
    const float* wi    = (const float*)d_in[7];
    const float* qnw   = (const float*)d_in[8];
    const float* knw   = (const float*)d_in[9];
    const float* Wproj = (const float*)d_in[10];
    float* out = (float*)d_out;

    // workspace (fits the proven >=256 MiB):
    //   [0,128)M   qkv fp32          -> after conv dead: [0,32) y, [32,64) y_pk, [64,80) Wproj_pk
    //   [128,256)M qt,kt,vt,it fp32  -> before conv: [128,144) x_pk, [144,176) Wqkv_pk
    char* ws = (char*)d_ws;
    const size_t MiB = 1048576;
    float* qkv      = (float*)(ws);
    float* y        = (float*)(ws);
    short* y_pk     = (short*)(ws + 32 * MiB);
    short* Wproj_pk = (short*)(ws + 64 * MiB);
    float* qt  = (float*)(ws + 128 * MiB);
    float* ktp = (float*)(ws + 160 * MiB);
    float* vtp = (float*)(ws + 192 * MiB);
    float* itp = (float*)(ws + 224 * MiB);
    short* x_pk     = (short*)(ws + 128 * MiB);
    short* Wqkv_pk  = (short*)(ws + 144 * MiB);

    // ---- stage A: qkv = x @ Wqkv (direct bf16 MFMA; error attenuated downstream) ----
    prep_a<<<dim3(64, 32), 256, 0, stream>>>(x, x_pk, 2048, 0);
    prep_b<<<dim3(64, 64), 256, 0, stream>>>(Wqkv, Wqkv_pk, 2048, 8192, 0);
    gemm_bf16<<<dim3(64, 32), 256, 0, stream>>>(x_pk, Wqkv_pk, qkv, 8192, 64, 64, 64, 0);

    // ---- stage B: conv + rmsnorm + rope + transpose ----
    conv_norm_rope<<<dim3(T_SEQ, NH, 2), 128, 0, stream>>>(
        qkv, wq, wk, wv, wi, qnw, knw, cosT, sinT, qt, ktp, vtp, itp);

    // ---- stage C: flash attention + sigmoid gate ----
    size_t smem = (size_t)(64 * QSTR + 2 * 32 * QSTR + 32 * PSTR) * sizeof(float);
    flash_attn<<<dim3(T_SEQ / 64, 2 * NH), 256, smem, stream>>>(qt, ktp, vtp, itp, y);

    // ---- stage D: out = y @ Wproj (bf16x2 3-term split: effectively fp32-exact) ----
    prep_a<<<dim3(64, 32), 256, 0, stream>>>(y, y_pk, 2048, 1);
    prep_b<<<dim3(64, 16), 256, 0, stream>>>(Wproj, Wproj_pk, 2048, 2048, 1);
    gemm_bf16<<<dim3(16, 32), 256, 0, stream>>>(y_pk, Wproj_pk, out, 2048, 128, 128, 192, 1);
}

// Round 3
// 1228.971 us; speedup vs baseline: 3.3462x; 1.9943x over previous
//
#include <hip/hip_runtime.h>
#include <stdint.h>

#define T_SEQ 2048
#define C_DIM 2048
#define NH    16
#define HD    128

typedef __attribute__((ext_vector_type(8))) short short8;
typedef __attribute__((ext_vector_type(4))) float f32x4;

__device__ __forceinline__ short f2bf(float f) {
    uint32_t x = __float_as_uint(f);
    uint32_t r = (x + 0x7fffu + ((x >> 16) & 1u)) >> 16;   // RNE
    return (short)r;
}
__device__ __forceinline__ float bf2f(short s) {
    return __uint_as_float(((uint32_t)(unsigned short)s) << 16);
}

// ============ prep A-side: fp32 [M][K] -> tiled bf16 [mblk][kb][128][32] (hi | optional lo) ============
__global__ __launch_bounds__(256) void prep_a(
    const float* __restrict__ X, short* __restrict__ Apk, int K, int split)
{
    const int kb = blockIdx.x, mblk = blockIdx.y, tid = threadIdx.x;
    const int kpb = K / 32;
    const int nkb = kpb << split;
    const int r0 = tid >> 3, c0 = (tid & 7) * 4;
    const size_t hiBase = ((size_t)mblk * nkb + kb) * 4096;
    const size_t loBase = hiBase + (size_t)kpb * 4096;
#pragma unroll
    for (int it = 0; it < 4; ++it) {
        const int row = it * 32 + r0;
        const float4 v = *(const float4*)&X[(size_t)(mblk * 128 + row) * K + kb * 32 + c0];
        float f[4] = { v.x, v.y, v.z, v.w };
        short h[4];
#pragma unroll
        for (int j = 0; j < 4; ++j) h[j] = f2bf(f[j]);
        *(int2*)&Apk[hiBase + row * 32 + c0] =
            make_int2((h[0] & 0xffff) | (h[1] << 16), (h[2] & 0xffff) | (h[3] << 16));
        if (split) {
            short l[4];
#pragma unroll
            for (int j = 0; j < 4; ++j) l[j] = f2bf(f[j] - bf2f(h[j]));
            *(int2*)&Apk[loBase + row * 32 + c0] =
                make_int2((l[0] & 0xffff) | (l[1] << 16), (l[2] & 0xffff) | (l[3] << 16));
        }
    }
}

// ============ prep B-side: fp32 [K][N] -> transposed tiled bf16 [nblk][kb][128n][32k] ============
__global__ __launch_bounds__(256) void prep_b(
    const float* __restrict__ W, short* __restrict__ Bpk, int K, int N, int split)
{
    const int kb = blockIdx.x, nblk = blockIdx.y, tid = threadIdx.x;
    const int kpb = K / 32;
    const int nkb = kpb << split;
    __shared__ float Ws[32][129];
    {
        const int r = tid >> 3, cbase = (tid & 7) * 4;
#pragma unroll
        for (int itc = 0; itc < 4; ++itc) {
            const int c = cbase + itc * 32;
            const float4 v = *(const float4*)&W[(size_t)(kb * 32 + r) * N + nblk * 128 + c];
            Ws[r][c] = v.x; Ws[r][c + 1] = v.y; Ws[r][c + 2] = v.z; Ws[r][c + 3] = v.w;
        }
    }
    __syncthreads();
    const int n = tid >> 1, ks = (tid & 1) * 16;
    const size_t hiBase = ((size_t)nblk * nkb + kb) * 4096;
    float f[16];
#pragma unroll
    for (int j = 0; j < 16; ++j) f[j] = Ws[ks + j][n];   // stride 129 -> conflict-free
    int hw[8];
#pragma unroll
    for (int j = 0; j < 8; ++j) {
        short a = f2bf(f[2 * j]), b = f2bf(f[2 * j + 1]);
        hw[j] = (a & 0xffff) | (b << 16);
    }
    *(int4*)&Bpk[hiBase + n * 32 + ks]     = make_int4(hw[0], hw[1], hw[2], hw[3]);
    *(int4*)&Bpk[hiBase + n * 32 + ks + 8] = make_int4(hw[4], hw[5], hw[6], hw[7]);
    if (split) {
        const size_t loBase = hiBase + (size_t)kpb * 4096;
        int lw[8];
#pragma unroll
        for (int j = 0; j < 8; ++j) {
            short ah = f2bf(f[2 * j]);     float ra = f[2 * j]     - bf2f(ah);
            short bh = f2bf(f[2 * j + 1]); float rb = f[2 * j + 1] - bf2f(bh);
            short a = f2bf(ra), b = f2bf(rb);
            lw[j] = (a & 0xffff) | (b << 16);
        }
        *(int4*)&Bpk[loBase + n * 32 + ks]     = make_int4(lw[0], lw[1], lw[2], lw[3]);
        *(int4*)&Bpk[loBase + n * 32 + ks + 8] = make_int4(lw[4], lw[5], lw[6], lw[7]);
    }
}

// ============ bf16 MFMA GEMM (unchanged from round 2, verified correct) ============
__global__ __launch_bounds__(256) void gemm_bf16(
    const short* __restrict__ Apk, const short* __restrict__ Bpk,
    float* __restrict__ C, int N, int nkbA, int nkbB, int nkb, int split)
{
    __shared__ short As[4096];
    __shared__ short Bs[4096];
    const int tid = threadIdx.x;
    const int lane = tid & 63, w = tid >> 6;
    const int wr = w >> 1, wc = w & 1;
    const int bm = blockIdx.y * 128, bn = blockIdx.x * 128;
    const size_t Abase = (size_t)blockIdx.y * nkbA * 4096;
    const size_t Bbase = (size_t)blockIdx.x * nkbB * 4096;
    const int r16 = lane & 15, q8 = (lane >> 4) * 8;

    const f32x4 zero = { 0.f, 0.f, 0.f, 0.f };
    f32x4 acc[4][4];
#pragma unroll
    for (int m = 0; m < 4; ++m)
#pragma unroll
        for (int n = 0; n < 4; ++n) acc[m][n] = zero;

    float4 ra[2], rb[2];
    {
        const short* ga = Apk + Abase;
        const short* gb = Bpk + Bbase;
#pragma unroll
        for (int i = 0; i < 2; ++i) {
            ra[i] = *(const float4*)(ga + i * 2048 + tid * 8);
            rb[i] = *(const float4*)(gb + i * 2048 + tid * 8);
        }
    }
    for (int vkb = 0; vkb < nkb; ++vkb) {
        __syncthreads();
#pragma unroll
        for (int i = 0; i < 2; ++i) {
            *(float4*)&As[i * 2048 + tid * 8] = ra[i];
            *(float4*)&Bs[i * 2048 + tid * 8] = rb[i];
        }
        __syncthreads();
        if (vkb + 1 < nkb) {
            const int nv = vkb + 1;
            int akb, bkb;
            if (split) { akb = (nv < 64) ? nv : nv - 64; bkb = (nv < 128) ? nv : nv - 128; }
            else       { akb = nv; bkb = nv; }
            const short* ga = Apk + Abase + (size_t)akb * 4096;
            const short* gb = Bpk + Bbase + (size_t)bkb * 4096;
#pragma unroll
            for (int i = 0; i < 2; ++i) {
                ra[i] = *(const float4*)(ga + i * 2048 + tid * 8);
                rb[i] = *(const float4*)(gb + i * 2048 + tid * 8);
            }
        }
        short8 af[4], bfr[4];
#pragma unroll
        for (int m = 0; m < 4; ++m)
            af[m] = *(const short8*)&As[(wr * 64 + m * 16 + r16) * 32 + q8];
#pragma unroll
        for (int n = 0; n < 4; ++n)
            bfr[n] = *(const short8*)&Bs[(wc * 64 + n * 16 + r16) * 32 + q8];
#pragma unroll
        for (int m = 0; m < 4; ++m)
#pragma unroll
            for (int n = 0; n < 4; ++n)
                acc[m][n] = __builtin_amdgcn_mfma_f32_16x16x32_bf16(af[m], bfr[n], acc[m][n], 0, 0, 0);
    }
    const int rq = lane >> 4;
#pragma unroll
    for (int m = 0; m < 4; ++m)
#pragma unroll
        for (int n = 0; n < 4; ++n) {
            const int col = bn + wc * 64 + n * 16 + r16;
#pragma unroll
            for (int j = 0; j < 4; ++j) {
                const int row = bm + wr * 64 + m * 16 + rq * 4 + j;
                C[(size_t)row * N + col] = acc[m][n][j];
            }
        }
}

// ===================== conv3 + rmsnorm + rope -> bf16 q,k (scale folded), bf16 V^T, fp32 intent ==========
__global__ __launch_bounds__(128) void conv_norm_rope(
    const float* __restrict__ qkv,
    const float* __restrict__ wq, const float* __restrict__ wk,
    const float* __restrict__ wv, const float* __restrict__ wi,
    const float* __restrict__ qnw, const float* __restrict__ knw,
    const float* __restrict__ cosT, const float* __restrict__ sinT,
    short* __restrict__ qt, short* __restrict__ kt,
    short* __restrict__ vtt, float* __restrict__ it)
{
    const int t = blockIdx.x, h = blockIdx.y, b = blockIdx.z;
    const int d = threadIdx.x;
    const int c = h * HD + d;
    const size_t rowbase = ((size_t)(b * T_SEQ + t)) * (4 * C_DIM);

    const float* Wt[4] = { wq, wk, wv, wi };
    float z[4];
#pragma unroll
    for (int s = 0; s < 4; ++s) {
        const float* w = Wt[s] + c * 3;
        float w0 = w[0], w1 = w[1], w2 = w[2];
        size_t idx = rowbase + (size_t)s * C_DIM + c;
        float x0 = qkv[idx];
        float x1 = (t >= 1) ? qkv[idx - (size_t)4 * C_DIM] : 0.f;
        float x2 = (t >= 2) ? qkv[idx - (size_t)8 * C_DIM] : 0.f;
        z[s] = fmaf(w0, x2, fmaf(w1, x1, w2 * x0));
    }

    float sq = z[0] * z[0], sk = z[1] * z[1];
#pragma unroll
    for (int off = 32; off > 0; off >>= 1) {
        sq += __shfl_down(sq, off);
        sk += __shfl_down(sk, off);
    }
    __shared__ float red[4];
    const int wid = threadIdx.x >> 6, lane = threadIdx.x & 63;
    if (lane == 0) { red[wid * 2 + 0] = sq; red[wid * 2 + 1] = sk; }
    __syncthreads();
    const float rq = rsqrtf((red[0] + red[2]) * (1.f / HD) + 1e-5f);
    const float rk = rsqrtf((red[1] + red[3]) * (1.f / HD) + 1e-5f);

    float zq = z[0] * rq * qnw[d];
    float zk = z[1] * rk * knw[d];
    float pq = __shfl_xor(zq, 1);
    float pk = __shfl_xor(zk, 1);
    float cv = cosT[t * (HD / 2) + (d >> 1)];
    float sv = sinT[t * (HD / 2) + (d >> 1)];
    float oq = (d & 1) ? (pq * sv + zq * cv) : (zq * cv - pq * sv);
    float ok = (d & 1) ? (pk * sv + zk * cv) : (zk * cv - pk * sv);
    oq *= 0.08838834764831845f;   // fold 1/sqrt(128) into q

    size_t o = ((size_t)(b * NH + h) * T_SEQ + t) * HD + d;
    qt[o] = f2bf(oq);
    kt[o] = f2bf(ok);
    vtt[((size_t)(b * NH + h) * HD + d) * T_SEQ + t] = f2bf(z[2]);   // V transposed [bh][d][t]
    it[o] = z[3];
}

// ===================== bf16 MFMA causal flash attention + sigmoid gate =====================
// 4 waves x 16 q-rows (BQ=64), BK=64. K tile [64][128] + V^T tile [128][64] in LDS with
// T2 XOR swizzle (byte ^= (row&7)<<4). P bounced through 2KB/wave swizzled LDS to re-layout
// C-layout -> A-fragment. Q A-frags hoisted in registers. 40KB LDS, 3 blocks/CU.
__global__ __launch_bounds__(256, 3) void flash_mfma(
    const short* __restrict__ qt, const short* __restrict__ kt,
    const short* __restrict__ vtt, const float* __restrict__ it,
    float* __restrict__ y)
{
    __shared__ short lds_k[8192];   // [64 key][128 d] bf16, swizzled
    __shared__ short lds_v[8192];   // [128 d][64 key] bf16, swizzled
    __shared__ short lds_p[4096];   // 4 waves x [16 row][64 key] bf16, swizzled

    const int tid = threadIdx.x;
    const int lane = tid & 63, w = tid >> 6;
    const int r16 = lane & 15, g = lane >> 4;          // g in 0..3

    // XCD-aware decode: blk%8 -> XCD; 4 bh per XCD keep that bh's K/V L2-resident.
    const int blk = blockIdx.x;
    const int xcd = blk & 7, idx = blk >> 3;
    const int bh = xcd * 4 + (idx & 3);
    const int qt_i = 31 - (idx >> 2);                  // heavy tiles first
    const int b = bh >> 4, h = bh & 15;
    const int q0 = qt_i * 64;
    const int qrow = q0 + w * 16;

    char* KsB = (char*)lds_k;
    char* VsB = (char*)lds_v;
    char* PsB = (char*)lds_p + w * 2048;

    // Q A-frags in registers: lane holds row=r16, k=g*8+j of each 32-chunk
    short8 qf[4];
    {
        const short* qp = qt + ((size_t)bh * T_SEQ + qrow + r16) * HD;
#pragma unroll
        for (int kc = 0; kc < 4; ++kc)
            qf[kc] = *(const short8*)(qp + kc * 32 + g * 8);
    }

    f32x4 o[8];
    float m[4], l[4];
#pragma unroll
    for (int dn = 0; dn < 8; ++dn) o[dn] = (f32x4){0.f, 0.f, 0.f, 0.f};
#pragma unroll
    for (int j = 0; j < 4; ++j) { m[j] = -1e30f; l[j] = 0.f; }

    const short* kbh = kt + (size_t)bh * T_SEQ * HD;
    const short* vbh = vtt + (size_t)bh * HD * T_SEQ;

    for (int kti = 0; kti <= qt_i; ++kti) {
        const int k0 = kti * 64;
        __syncthreads();   // previous iteration's LDS reads complete
        // ---- stage K [64][128] ----
#pragma unroll
        for (int i = 0; i < 4; ++i) {
            const int ix = tid + i * 256;              // 0..1023
            const int row = ix >> 4, dch = ix & 15;
            short8 v = *(const short8*)(kbh + (size_t)(k0 + row) * HD + dch * 8);
            *(short8*)(KsB + row * 256 + ((dch * 16) ^ ((row & 7) << 4))) = v;
        }
        // ---- stage V^T [128][64] ----
#pragma unroll
        for (int i = 0; i < 4; ++i) {
            const int ix = tid + i * 256;
            const int dr = ix >> 3, kch = ix & 7;
            short8 v = *(const short8*)(vbh + (size_t)dr * T_SEQ + k0 + kch * 8);
            *(short8*)(VsB + dr * 128 + ((kch * 16) ^ ((dr & 7) << 4))) = v;
        }
        __syncthreads();

        // ---- QK^T: S[16 q][64 key] per wave ----
        f32x4 sacc[4];
#pragma unroll
        for (int nt = 0; nt < 4; ++nt) sacc[nt] = (f32x4){0.f, 0.f, 0.f, 0.f};
#pragma unroll
        for (int nt = 0; nt < 4; ++nt) {
            const int key = nt * 16 + r16;
#pragma unroll
            for (int kc = 0; kc < 4; ++kc) {
                const short8 kf = *(const short8*)(KsB + key * 256 +
                                    ((kc * 64 + g * 16) ^ ((r16 & 7) << 4)));
                sacc[nt] = __builtin_amdgcn_mfma_f32_16x16x32_bf16(qf[kc], kf, sacc[nt], 0, 0, 0);
            }
        }

        // ---- online softmax (scale pre-folded into q) ----
        const bool diag = (kti == qt_i);
#pragma unroll
        for (int j = 0; j < 4; ++j) {
            const int qi = qrow + g * 4 + j;
            float s0 = sacc[0][j], s1 = sacc[1][j], s2 = sacc[2][j], s3 = sacc[3][j];
            if (diag) {
                if (k0 +      r16 > qi) s0 = -1e30f;
                if (k0 + 16 + r16 > qi) s1 = -1e30f;
                if (k0 + 32 + r16 > qi) s2 = -1e30f;
                if (k0 + 48 + r16 > qi) s3 = -1e30f;
            }
            float mx = fmaxf(fmaxf(s0, s1), fmaxf(s2, s3));
            mx = fmaxf(mx, __shfl_xor(mx, 1));
            mx = fmaxf(mx, __shfl_xor(mx, 2));
            mx = fmaxf(mx, __shfl_xor(mx, 4));
            mx = fmaxf(mx, __shfl_xor(mx, 8));
            const float mn = fmaxf(m[j], mx);
            const float corr = __expf(m[j] - mn);
            m[j] = mn;
            float p0 = __expf(s0 - mn), p1 = __expf(s1 - mn);
            float p2 = __expf(s2 - mn), p3 = __expf(s3 - mn);
            float ps = p0 + p1 + p2 + p3;
            ps += __shfl_xor(ps, 1);
            ps += __shfl_xor(ps, 2);
            ps += __shfl_xor(ps, 4);
            ps += __shfl_xor(ps, 8);
            l[j] = l[j] * corr + ps;
#pragma unroll
            for (int dn = 0; dn < 8; ++dn) o[dn][j] *= corr;
            // P -> bf16 -> wave-private swizzled LDS [row][key]
            const int row = g * 4 + j;
            const int rsw = (row & 7) << 4;
            *(short*)(PsB + row * 128 + ((0  + r16 * 2) ^ rsw)) = f2bf(p0);
            *(short*)(PsB + row * 128 + ((32 + r16 * 2) ^ rsw)) = f2bf(p1);
            *(short*)(PsB + row * 128 + ((64 + r16 * 2) ^ rsw)) = f2bf(p2);
            *(short*)(PsB + row * 128 + ((96 + r16 * 2) ^ rsw)) = f2bf(p3);
        }

        // ---- PV: O[16 q][128 d] += P @ V ----
        short8 pf[2];
#pragma unroll
        for (int kc2 = 0; kc2 < 2; ++kc2)
            pf[kc2] = *(const short8*)(PsB + r16 * 128 +
                        ((kc2 * 64 + g * 16) ^ ((r16 & 7) << 4)));
#pragma unroll
        for (int dn = 0; dn < 8; ++dn) {
            const int d = dn * 16 + r16;
#pragma unroll
            for (int kc2 = 0; kc2 < 2; ++kc2) {
                const short8 vf = *(const short8*)(VsB + d * 128 +
                                    ((kc2 * 64 + g * 16) ^ ((r16 & 7) << 4)));
                o[dn] = __builtin_amdgcn_mfma_f32_16x16x32_bf16(pf[kc2], vf, o[dn], 0, 0, 0);
            }
        }
    }

    // ---- epilogue: normalize, sigmoid(intent) gate, store fp32 y[b][t][h*128+d] ----
#pragma unroll
    for (int j = 0; j < 4; ++j) {
        const float inv = 1.f / l[j];
        const int t = qrow + g * 4 + j;
        const float* ip = it + ((size_t)bh * T_SEQ + t) * HD;
        float* yp = y + ((size_t)(b * T_SEQ + t)) * C_DIM + h * HD;
#pragma unroll
        for (int dn = 0; dn < 8; ++dn) {
            const int d = dn * 16 + r16;
            const float gate = 1.f / (1.f + __expf(-ip[d]));
            yp[d] = o[dn][j] * inv * gate;
        }
    }
}

// ===================== launch =====================
extern "C" void kernel_launch(void* const* d_in, const int* in_sizes, int n_in,
                              void* d_out, int out_size, void* d_ws, size_t ws_size,
                              hipStream_t stream)
{
    const float* x     = (const float*)d_in[0];
    const float* cosT  = (const float*)d_in[1];
    const float* sinT  = (const float*)d_in[2];
    const float* Wqkv  = (const float*)d_in[3];
    const float* wq    = (const float*)d_in[4];
    const float* wk    = (const float*)d_in[5];
    const float* wv    = (const float*)d_in[6];
    const float* wi    = (const float*)d_in[7];
    const float* qnw   = (const float*)d_in[8];
    const float* knw   = (const float*)d_in[9];
    const float* Wproj = (const float*)d_in[10];
    float* out = (float*)d_out;

    // workspace:
    //  [0,128)M   qkv fp32 -> after conv dead: [0,32) y fp32, [32,64) y_pk, [64,80) Wproj_pk
    //  [128,208)M qt bf16(16M) | kt bf16(16M) | vtt bf16(16M) | itp fp32(32M)
    //  (pre-conv, same region: [128,144) x_pk, [144,176) Wqkv_pk — consumed by gemm A first)
    char* ws = (char*)d_ws;
    const size_t MiB = 1048576;
    float* qkv      = (float*)(ws);
    float* y        = (float*)(ws);
    short* y_pk     = (short*)(ws + 32 * MiB);
    short* Wproj_pk = (short*)(ws + 64 * MiB);
    short* qt  = (short*)(ws + 128 * MiB);
    short* ktp = (short*)(ws + 144 * MiB);
    short* vtt = (short*)(ws + 160 * MiB);
    float* itp = (float*)(ws + 176 * MiB);
    short* x_pk     = (short*)(ws + 128 * MiB);
    short* Wqkv_pk  = (short*)(ws + 144 * MiB);

    // ---- stage A: qkv = x @ Wqkv (bf16 MFMA) ----
    prep_a<<<dim3(64, 32), 256, 0, stream>>>(x, x_pk, 2048, 0);
    prep_b<<<dim3(64, 64), 256, 0, stream>>>(Wqkv, Wqkv_pk, 2048, 8192, 0);
    gemm_bf16<<<dim3(64, 32), 256, 0, stream>>>(x_pk, Wqkv_pk, qkv, 8192, 64, 64, 64, 0);

    // ---- stage B: conv + rmsnorm + rope -> bf16 q,k,V^T + fp32 intent ----
    conv_norm_rope<<<dim3(T_SEQ, NH, 2), 128, 0, stream>>>(
        qkv, wq, wk, wv, wi, qnw, knw, cosT, sinT, qt, ktp, vtt, itp);

    // ---- stage C: bf16 MFMA flash attention + sigmoid gate ----
    flash_mfma<<<dim3(32 * 32), 256, 0, stream>>>(qt, ktp, vtt, itp, y);

    // ---- stage D: out = y @ Wproj (bf16x2 3-term split) ----
    prep_a<<<dim3(64, 32), 256, 0, stream>>>(y, y_pk, 2048, 1);
    prep_b<<<dim3(64, 16), 256, 0, stream>>>(Wproj, Wproj_pk, 2048, 2048, 1);
    gemm_bf16<<<dim3(16, 32), 256, 0, stream>>>(y_pk, Wproj_pk, out, 2048, 128, 128, 192, 1);
}

// Round 4
// 612.455 us; speedup vs baseline: 6.7145x; 2.0066x over previous
//
#include <hip/hip_runtime.h>
#include <stdint.h>

#define T_SEQ 2048
#define C_DIM 2048
#define NH    16
#define HD    128

typedef __attribute__((ext_vector_type(8))) short short8;
typedef __attribute__((ext_vector_type(4))) float f32x4;

#if defined(__has_builtin)
# if __has_builtin(__builtin_amdgcn_global_load_lds)
#  define HAVE_GLL 1
# endif
#endif
#ifndef HAVE_GLL
# define HAVE_GLL 0
#endif

__device__ __forceinline__ short f2bf(float f) {
    uint32_t x = __float_as_uint(f);
    uint32_t r = (x + 0x7fffu + ((x >> 16) & 1u)) >> 16;   // RNE
    return (short)r;
}
__device__ __forceinline__ float bf2f(short s) {
    return __uint_as_float(((uint32_t)(unsigned short)s) << 16);
}

// async global->LDS, 16B/lane; LDS dst is wave-uniform base, HW adds lane*16.
__device__ __forceinline__ void gload16(const short* g, short* l) {
    const int lane = threadIdx.x & 63;
#if HAVE_GLL
    __builtin_amdgcn_global_load_lds(
        (const __attribute__((address_space(1))) void*)(g + lane * 8),
        (__attribute__((address_space(3))) void*)l, 16, 0, 0);
#else
    *(short8*)(l + lane * 8) = *(const short8*)(g + lane * 8);
#endif
}

// ============ prep A-side: fp32 [M][K] -> fragment-ordered bf16 tiles ============
// tile (mblk,kb) = 128 rows x 32 k; layout [fm=row>>4][lane=(kc<<4)|(row&15)][j=k&7]
// so LDS copy is byte-identical and fragment ds_read is lane-linear (conflict-free).
__global__ __launch_bounds__(256) void prep_a(
    const float* __restrict__ X, short* __restrict__ Apk, int K, int split)
{
    const int kb = blockIdx.x, mblk = blockIdx.y, tid = threadIdx.x;
    const int kpb = K / 32;
    const int nkb = kpb << split;
    const size_t hiBase = ((size_t)mblk * nkb + kb) * 4096;
    const size_t loBase = hiBase + (size_t)kpb * 4096;
#pragma unroll
    for (int itr = 0; itr < 2; ++itr) {
        const int item = itr * 256 + tid;          // 0..511 = 128 rows x 4 kchunks
        const int row = item >> 2, kc = item & 3;
        const float* xp = &X[(size_t)(mblk * 128 + row) * K + kb * 32 + kc * 8];
        float4 v0 = *(const float4*)xp;
        float4 v1 = *(const float4*)(xp + 4);
        float f[8] = { v0.x, v0.y, v0.z, v0.w, v1.x, v1.y, v1.z, v1.w };
        const size_t off = (size_t)(row >> 4) * 512 + (size_t)((kc << 4) | (row & 15)) * 8;
        short h[8];
#pragma unroll
        for (int j = 0; j < 8; ++j) h[j] = f2bf(f[j]);
        int hw[4];
#pragma unroll
        for (int j = 0; j < 4; ++j) hw[j] = (h[2*j] & 0xffff) | (h[2*j+1] << 16);
        *(int4*)&Apk[hiBase + off] = make_int4(hw[0], hw[1], hw[2], hw[3]);
        if (split) {
            int lw[4];
#pragma unroll
            for (int j = 0; j < 4; ++j) {
                short a = f2bf(f[2*j]   - bf2f(h[2*j]));
                short b = f2bf(f[2*j+1] - bf2f(h[2*j+1]));
                lw[j] = (a & 0xffff) | (b << 16);
            }
            *(int4*)&Apk[loBase + off] = make_int4(lw[0], lw[1], lw[2], lw[3]);
        }
    }
}

// ============ prep B-side: fp32 [K][N] -> fragment-ordered bf16 tiles (transposed) ============
// tile (nblk,kb) = 128 n x 32 k; same fragment layout with n in place of row.
__global__ __launch_bounds__(256) void prep_b(
    const float* __restrict__ W, short* __restrict__ Bpk, int K, int N, int split)
{
    const int kb = blockIdx.x, nblk = blockIdx.y, tid = threadIdx.x;
    const int kpb = K / 32;
    const int nkb = kpb << split;
    __shared__ float Ws[32][129];
    {
        const int r = tid >> 3, cbase = (tid & 7) * 4;
#pragma unroll
        for (int itc = 0; itc < 4; ++itc) {
            const int c = cbase + itc * 32;
            const float4 v = *(const float4*)&W[(size_t)(kb * 32 + r) * N + nblk * 128 + c];
            Ws[r][c] = v.x; Ws[r][c + 1] = v.y; Ws[r][c + 2] = v.z; Ws[r][c + 3] = v.w;
        }
    }
    __syncthreads();
    const size_t hiBase = ((size_t)nblk * nkb + kb) * 4096;
    const size_t loBase = hiBase + (size_t)kpb * 4096;
#pragma unroll
    for (int itr = 0; itr < 2; ++itr) {
        const int item = itr * 256 + tid;
        const int n = item >> 2, kc = item & 3;
        float f[8];
#pragma unroll
        for (int j = 0; j < 8; ++j) f[j] = Ws[kc * 8 + j][n];
        const size_t off = (size_t)(n >> 4) * 512 + (size_t)((kc << 4) | (n & 15)) * 8;
        short h[8];
#pragma unroll
        for (int j = 0; j < 8; ++j) h[j] = f2bf(f[j]);
        int hw[4];
#pragma unroll
        for (int j = 0; j < 4; ++j) hw[j] = (h[2*j] & 0xffff) | (h[2*j+1] << 16);
        *(int4*)&Bpk[hiBase + off] = make_int4(hw[0], hw[1], hw[2], hw[3]);
        if (split) {
            int lw[4];
#pragma unroll
            for (int j = 0; j < 4; ++j) {
                short a = f2bf(f[2*j]   - bf2f(h[2*j]));
                short b = f2bf(f[2*j+1] - bf2f(h[2*j+1]));
                lw[j] = (a & 0xffff) | (b << 16);
            }
            *(int4*)&Bpk[loBase + off] = make_int4(lw[0], lw[1], lw[2], lw[3]);
        }
    }
}

// ============ bf16 MFMA GEMM, m97 structure: fragment-ordered tiles + global_load_lds w16 ============
// 128x128 tile, BK=32, 4 waves (2x2), 16 MFMA + 8 lane-linear ds_read_b128 per K-step.
// split=1: virtual kb in [0,192) = Ahi@Bhi | Ahi@Blo | Alo@Bhi (kpb=64 hardcoded).
__global__ __launch_bounds__(256) void gemm_bf16(
    const short* __restrict__ Apk, const short* __restrict__ Bpk,
    float* __restrict__ C, int N, int gx, int nkbA, int nkbB, int nkb, int split)
{
    __shared__ __align__(16) char smem[16384];
    short* As = (short*)smem;           // 8 KB tile, fragment order
    short* Bs = (short*)(smem + 8192);
    const int tid = threadIdx.x;
    const int lane = tid & 63, w = tid >> 6;
    const int wr = w >> 1, wc = w & 1;

    // bijective XCD swizzle (nwg % 8 == 0), bx-major: each XCD holds few B-panels in L2
    const int nwg = gridDim.x, cpx = nwg >> 3, bid = blockIdx.x;
    const int swz = (bid & 7) * cpx + (bid >> 3);
    const int gy = nwg / gx;
    const int by = swz % gy, bx = swz / gy;
    const int bm = by * 128, bn = bx * 128;
    const size_t Abase = (size_t)by * nkbA * 4096;
    const size_t Bbase = (size_t)bx * nkbB * 4096;

    f32x4 acc[4][4];
#pragma unroll
    for (int m = 0; m < 4; ++m)
#pragma unroll
        for (int n = 0; n < 4; ++n) acc[m][n] = (f32x4){0.f, 0.f, 0.f, 0.f};

    for (int vkb = 0; vkb < nkb; ++vkb) {
        int akb, bkb;
        if (split) { akb = (vkb < 64) ? vkb : vkb - 64; bkb = (vkb < 128) ? vkb : vkb - 128; }
        else       { akb = vkb; bkb = vkb; }
        const short* ga = Apk + Abase + (size_t)akb * 4096;
        const short* gb = Bpk + Bbase + (size_t)bkb * 4096;
        __syncthreads();                       // prev frag reads done
#pragma unroll
        for (int i = 0; i < 2; ++i) {
            gload16(ga + w * 1024 + i * 512, As + w * 1024 + i * 512);
            gload16(gb + w * 1024 + i * 512, Bs + w * 1024 + i * 512);
        }
        __syncthreads();                       // vmcnt(0) drained by compiler

        short8 af[4], bfr[4];
#pragma unroll
        for (int m = 0; m < 4; ++m)
            af[m] = *(const short8*)&As[(wr * 4 + m) * 512 + lane * 8];
#pragma unroll
        for (int n = 0; n < 4; ++n)
            bfr[n] = *(const short8*)&Bs[(wc * 4 + n) * 512 + lane * 8];
#pragma unroll
        for (int m = 0; m < 4; ++m)
#pragma unroll
            for (int n = 0; n < 4; ++n)
                acc[m][n] = __builtin_amdgcn_mfma_f32_16x16x32_bf16(af[m], bfr[n], acc[m][n], 0, 0, 0);
    }

    // ---- vectorized epilogue: bounce 32x128 fp32 chunks through LDS, float4 stores ----
    float* Cs = (float*)smem;                  // 32 rows x 128 cols = 16 KB
    const int rq = lane >> 4, r16 = lane & 15;
#pragma unroll
    for (int m = 0; m < 4; ++m) {
        __syncthreads();                       // LDS free (K-loop / prev chunk done)
#pragma unroll
        for (int n = 0; n < 4; ++n)
#pragma unroll
            for (int j = 0; j < 4; ++j)
                Cs[(wr * 16 + rq * 4 + j) * 128 + wc * 64 + n * 16 + r16] = acc[m][n][j];
        __syncthreads();
#pragma unroll
        for (int it2 = 0; it2 < 4; ++it2) {
            const int idx = it2 * 256 + tid;
            const int lr = idx >> 5, c4 = (idx & 31) * 4;
            const int grow = bm + (lr >> 4) * 64 + m * 16 + (lr & 15);
            *(float4*)&C[(size_t)grow * N + bn + c4] = *(const float4*)&Cs[lr * 128 + c4];
        }
    }
}

// ===================== conv3 + rmsnorm + rope -> bf16 q,k (scale folded), bf16 V^T, fp32 intent ==========
__global__ __launch_bounds__(128) void conv_norm_rope(
    const float* __restrict__ qkv,
    const float* __restrict__ wq, const float* __restrict__ wk,
    const float* __restrict__ wv, const float* __restrict__ wi,
    const float* __restrict__ qnw, const float* __restrict__ knw,
    const float* __restrict__ cosT, const float* __restrict__ sinT,
    short* __restrict__ qt, short* __restrict__ kt,
    short* __restrict__ vtt, float* __restrict__ it)
{
    const int t = blockIdx.x, h = blockIdx.y, b = blockIdx.z;
    const int d = threadIdx.x;
    const int c = h * HD + d;
    const size_t rowbase = ((size_t)(b * T_SEQ + t)) * (4 * C_DIM);

    const float* Wt[4] = { wq, wk, wv, wi };
    float z[4];
#pragma unroll
    for (int s = 0; s < 4; ++s) {
        const float* w = Wt[s] + c * 3;
        float w0 = w[0], w1 = w[1], w2 = w[2];
        size_t idx = rowbase + (size_t)s * C_DIM + c;
        float x0 = qkv[idx];
        float x1 = (t >= 1) ? qkv[idx - (size_t)4 * C_DIM] : 0.f;
        float x2 = (t >= 2) ? qkv[idx - (size_t)8 * C_DIM] : 0.f;
        z[s] = fmaf(w0, x2, fmaf(w1, x1, w2 * x0));
    }

    float sq = z[0] * z[0], sk = z[1] * z[1];
#pragma unroll
    for (int off = 32; off > 0; off >>= 1) {
        sq += __shfl_down(sq, off);
        sk += __shfl_down(sk, off);
    }
    __shared__ float red[4];
    const int wid = threadIdx.x >> 6, lane = threadIdx.x & 63;
    if (lane == 0) { red[wid * 2 + 0] = sq; red[wid * 2 + 1] = sk; }
    __syncthreads();
    const float rq = rsqrtf((red[0] + red[2]) * (1.f / HD) + 1e-5f);
    const float rk = rsqrtf((red[1] + red[3]) * (1.f / HD) + 1e-5f);

    float zq = z[0] * rq * qnw[d];
    float zk = z[1] * rk * knw[d];
    float pq = __shfl_xor(zq, 1);
    float pk = __shfl_xor(zk, 1);
    float cv = cosT[t * (HD / 2) + (d >> 1)];
    float sv = sinT[t * (HD / 2) + (d >> 1)];
    float oq = (d & 1) ? (pq * sv + zq * cv) : (zq * cv - pq * sv);
    float ok = (d & 1) ? (pk * sv + zk * cv) : (zk * cv - pk * sv);
    oq *= 0.08838834764831845f;   // fold 1/sqrt(128) into q

    size_t o = ((size_t)(b * NH + h) * T_SEQ + t) * HD + d;
    qt[o] = f2bf(oq);
    kt[o] = f2bf(ok);
    vtt[((size_t)(b * NH + h) * HD + d) * T_SEQ + t] = f2bf(z[2]);   // V transposed [bh][d][t]
    it[o] = z[3];
}

// ===================== bf16 MFMA causal flash attention + sigmoid gate (unchanged, verified) ==========
__global__ __launch_bounds__(256, 3) void flash_mfma(
    const short* __restrict__ qt, const short* __restrict__ kt,
    const short* __restrict__ vtt, const float* __restrict__ it,
    float* __restrict__ y)
{
    __shared__ short lds_k[8192];   // [64 key][128 d] bf16, swizzled
    __shared__ short lds_v[8192];   // [128 d][64 key] bf16, swizzled
    __shared__ short lds_p[4096];   // 4 waves x [16 row][64 key] bf16, swizzled

    const int tid = threadIdx.x;
    const int lane = tid & 63, w = tid >> 6;
    const int r16 = lane & 15, g = lane >> 4;

    const int blk = blockIdx.x;
    const int xcd = blk & 7, idx = blk >> 3;
    const int bh = xcd * 4 + (idx & 3);
    const int qt_i = 31 - (idx >> 2);
    const int b = bh >> 4, h = bh & 15;
    const int q0 = qt_i * 64;
    const int qrow = q0 + w * 16;

    char* KsB = (char*)lds_k;
    char* VsB = (char*)lds_v;
    char* PsB = (char*)lds_p + w * 2048;

    short8 qf[4];
    {
        const short* qp = qt + ((size_t)bh * T_SEQ + qrow + r16) * HD;
#pragma unroll
        for (int kc = 0; kc < 4; ++kc)
            qf[kc] = *(const short8*)(qp + kc * 32 + g * 8);
    }

    f32x4 o[8];
    float m[4], l[4];
#pragma unroll
    for (int dn = 0; dn < 8; ++dn) o[dn] = (f32x4){0.f, 0.f, 0.f, 0.f};
#pragma unroll
    for (int j = 0; j < 4; ++j) { m[j] = -1e30f; l[j] = 0.f; }

    const short* kbh = kt + (size_t)bh * T_SEQ * HD;
    const short* vbh = vtt + (size_t)bh * HD * T_SEQ;

    for (int kti = 0; kti <= qt_i; ++kti) {
        const int k0 = kti * 64;
        __syncthreads();
#pragma unroll
        for (int i = 0; i < 4; ++i) {
            const int ix = tid + i * 256;
            const int row = ix >> 4, dch = ix & 15;
            short8 v = *(const short8*)(kbh + (size_t)(k0 + row) * HD + dch * 8);
            *(short8*)(KsB + row * 256 + ((dch * 16) ^ ((row & 7) << 4))) = v;
        }
#pragma unroll
        for (int i = 0; i < 4; ++i) {
            const int ix = tid + i * 256;
            const int dr = ix >> 3, kch = ix & 7;
            short8 v = *(const short8*)(vbh + (size_t)dr * T_SEQ + k0 + kch * 8);
            *(short8*)(VsB + dr * 128 + ((kch * 16) ^ ((dr & 7) << 4))) = v;
        }
        __syncthreads();

        f32x4 sacc[4];
#pragma unroll
        for (int nt = 0; nt < 4; ++nt) sacc[nt] = (f32x4){0.f, 0.f, 0.f, 0.f};
#pragma unroll
        for (int nt = 0; nt < 4; ++nt) {
            const int key = nt * 16 + r16;
#pragma unroll
            for (int kc = 0; kc < 4; ++kc) {
                const short8 kf = *(const short8*)(KsB + key * 256 +
                                    ((kc * 64 + g * 16) ^ ((r16 & 7) << 4)));
                sacc[nt] = __builtin_amdgcn_mfma_f32_16x16x32_bf16(qf[kc], kf, sacc[nt], 0, 0, 0);
            }
        }

        const bool diag = (kti == qt_i);
#pragma unroll
        for (int j = 0; j < 4; ++j) {
            const int qi = qrow + g * 4 + j;
            float s0 = sacc[0][j], s1 = sacc[1][j], s2 = sacc[2][j], s3 = sacc[3][j];
            if (diag) {
                if (k0 +      r16 > qi) s0 = -1e30f;
                if (k0 + 16 + r16 > qi) s1 = -1e30f;
                if (k0 + 32 + r16 > qi) s2 = -1e30f;
                if (k0 + 48 + r16 > qi) s3 = -1e30f;
            }
            float mx = fmaxf(fmaxf(s0, s1), fmaxf(s2, s3));
            mx = fmaxf(mx, __shfl_xor(mx, 1));
            mx = fmaxf(mx, __shfl_xor(mx, 2));
            mx = fmaxf(mx, __shfl_xor(mx, 4));
            mx = fmaxf(mx, __shfl_xor(mx, 8));
            const float mn = fmaxf(m[j], mx);
            const float corr = __expf(m[j] - mn);
            m[j] = mn;
            float p0 = __expf(s0 - mn), p1 = __expf(s1 - mn);
            float p2 = __expf(s2 - mn), p3 = __expf(s3 - mn);
            float ps = p0 + p1 + p2 + p3;
            ps += __shfl_xor(ps, 1);
            ps += __shfl_xor(ps, 2);
            ps += __shfl_xor(ps, 4);
            ps += __shfl_xor(ps, 8);
            l[j] = l[j] * corr + ps;
#pragma unroll
            for (int dn = 0; dn < 8; ++dn) o[dn][j] *= corr;
            const int row = g * 4 + j;
            const int rsw = (row & 7) << 4;
            *(short*)(PsB + row * 128 + ((0  + r16 * 2) ^ rsw)) = f2bf(p0);
            *(short*)(PsB + row * 128 + ((32 + r16 * 2) ^ rsw)) = f2bf(p1);
            *(short*)(PsB + row * 128 + ((64 + r16 * 2) ^ rsw)) = f2bf(p2);
            *(short*)(PsB + row * 128 + ((96 + r16 * 2) ^ rsw)) = f2bf(p3);
        }

        short8 pf[2];
#pragma unroll
        for (int kc2 = 0; kc2 < 2; ++kc2)
            pf[kc2] = *(const short8*)(PsB + r16 * 128 +
                        ((kc2 * 64 + g * 16) ^ ((r16 & 7) << 4)));
#pragma unroll
        for (int dn = 0; dn < 8; ++dn) {
            const int d = dn * 16 + r16;
#pragma unroll
            for (int kc2 = 0; kc2 < 2; ++kc2) {
                const short8 vf = *(const short8*)(VsB + d * 128 +
                                    ((kc2 * 64 + g * 16) ^ ((r16 & 7) << 4)));
                o[dn] = __builtin_amdgcn_mfma_f32_16x16x32_bf16(pf[kc2], vf, o[dn], 0, 0, 0);
            }
        }
    }

#pragma unroll
    for (int j = 0; j < 4; ++j) {
        const float inv = 1.f / l[j];
        const int t = qrow + g * 4 + j;
        const float* ip = it + ((size_t)bh * T_SEQ + t) * HD;
        float* yp = y + ((size_t)(b * T_SEQ + t)) * C_DIM + h * HD;
#pragma unroll
        for (int dn = 0; dn < 8; ++dn) {
            const int d = dn * 16 + r16;
            const float gate = 1.f / (1.f + __expf(-ip[d]));
            yp[d] = o[dn][j] * inv * gate;
        }
    }
}

// ===================== launch =====================
extern "C" void kernel_launch(void* const* d_in, const int* in_sizes, int n_in,
                              void* d_out, int out_size, void* d_ws, size_t ws_size,
                              hipStream_t stream)
{
    const float* x     = (const float*)d_in[0];
    const float* cosT  = (const float*)d_in[1];
    const float* sinT  = (const float*)d_in[2];
    const float* Wqkv  = (const float*)d_in[3];
    const float* wq    = (const float*)d_in[4];
    const float* wk    = (const float*)d_in[5];
    const float* wv    = (const float*)d_in[6];
    const float* wi    = (const float*)d_in[7];
    const float* qnw   = (const float*)d_in[8];
    const float* knw   = (const float*)d_in[9];
    const float* Wproj = (const float*)d_in[10];
    float* out = (float*)d_out;

    char* ws = (char*)d_ws;
    const size_t MiB = 1048576;
    float* qkv      = (float*)(ws);
    float* y        = (float*)(ws);
    short* y_pk     = (short*)(ws + 32 * MiB);
    short* Wproj_pk = (short*)(ws + 64 * MiB);
    short* qt  = (short*)(ws + 128 * MiB);
    short* ktp = (short*)(ws + 144 * MiB);
    short* vtt = (short*)(ws + 160 * MiB);
    float* itp = (float*)(ws + 176 * MiB);
    short* x_pk     = (short*)(ws + 128 * MiB);
    short* Wqkv_pk  = (short*)(ws + 144 * MiB);

    // ---- stage A: qkv = x @ Wqkv (bf16 MFMA, m97 structure) ----
    prep_a<<<dim3(64, 32), 256, 0, stream>>>(x, x_pk, 2048, 0);
    prep_b<<<dim3(64, 64), 256, 0, stream>>>(Wqkv, Wqkv_pk, 2048, 8192, 0);
    gemm_bf16<<<dim3(2048), 256, 0, stream>>>(x_pk, Wqkv_pk, qkv, 8192, 64, 64, 64, 64, 0);

    // ---- stage B: conv + rmsnorm + rope -> bf16 q,k,V^T + fp32 intent ----
    conv_norm_rope<<<dim3(T_SEQ, NH, 2), 128, 0, stream>>>(
        qkv, wq, wk, wv, wi, qnw, knw, cosT, sinT, qt, ktp, vtt, itp);

    // ---- stage C: bf16 MFMA flash attention + sigmoid gate ----
    flash_mfma<<<dim3(32 * 32), 256, 0, stream>>>(qt, ktp, vtt, itp, y);

    // ---- stage D: out = y @ Wproj (bf16x2 3-term split) ----
    prep_a<<<dim3(64, 32), 256, 0, stream>>>(y, y_pk, 2048, 1);
    prep_b<<<dim3(64, 16), 256, 0, stream>>>(Wproj, Wproj_pk, 2048, 2048, 1);
    gemm_bf16<<<dim3(512), 256, 0, stream>>>(y_pk, Wproj_pk, out, 2048, 16, 128, 128, 192, 1);
}

// Round 5
// 549.347 us; speedup vs baseline: 7.4858x; 1.1149x over previous
//
#include <hip/hip_runtime.h>
#include <stdint.h>

#define T_SEQ 2048
#define C_DIM 2048
#define NH    16
#define HD    128

typedef __attribute__((ext_vector_type(8))) short short8;
typedef __attribute__((ext_vector_type(4))) float f32x4;

#if defined(__has_builtin)
# if __has_builtin(__builtin_amdgcn_global_load_lds)
#  define HAVE_GLL 1
# endif
#endif
#ifndef HAVE_GLL
# define HAVE_GLL 0
#endif

__device__ __forceinline__ short f2bf(float f) {
    uint32_t x = __float_as_uint(f);
    uint32_t r = (x + 0x7fffu + ((x >> 16) & 1u)) >> 16;   // RNE
    return (short)r;
}
__device__ __forceinline__ float bf2f(short s) {
    return __uint_as_float(((uint32_t)(unsigned short)s) << 16);
}

// async global->LDS, 16B/lane; LDS dst is wave-uniform base, HW adds lane*16.
__device__ __forceinline__ void gload16(const short* g, short* l) {
    const int lane = threadIdx.x & 63;
#if HAVE_GLL
    __builtin_amdgcn_global_load_lds(
        (const __attribute__((address_space(1))) void*)(g + lane * 8),
        (__attribute__((address_space(3))) void*)l, 16, 0, 0);
#else
    *(short8*)(l + lane * 8) = *(const short8*)(g + lane * 8);
#endif
}

// ============ prep A-side: fp32 [M][K] -> fragment-ordered bf16 tiles ============
// tile (mblk,kb) = 128 rows x 32 k; layout [fm=row>>4][lane=(kc<<4)|(row&15)][j=k&7]
// so LDS copy is byte-identical and fragment ds_read is lane-linear (conflict-free).
__global__ __launch_bounds__(256) void prep_a(
    const float* __restrict__ X, short* __restrict__ Apk, int K, int split)
{
    const int kb = blockIdx.x, mblk = blockIdx.y, tid = threadIdx.x;
    const int kpb = K / 32;
    const int nkb = kpb << split;
    const size_t hiBase = ((size_t)mblk * nkb + kb) * 4096;
    const size_t loBase = hiBase + (size_t)kpb * 4096;
#pragma unroll
    for (int itr = 0; itr < 2; ++itr) {
        const int item = itr * 256 + tid;          // 0..511 = 128 rows x 4 kchunks
        const int row = item >> 2, kc = item & 3;
        const float* xp = &X[(size_t)(mblk * 128 + row) * K + kb * 32 + kc * 8];
        float4 v0 = *(const float4*)xp;
        float4 v1 = *(const float4*)(xp + 4);
        float f[8] = { v0.x, v0.y, v0.z, v0.w, v1.x, v1.y, v1.z, v1.w };
        const size_t off = (size_t)(row >> 4) * 512 + (size_t)((kc << 4) | (row & 15)) * 8;
        short h[8];
#pragma unroll
        for (int j = 0; j < 8; ++j) h[j] = f2bf(f[j]);
        int hw[4];
#pragma unroll
        for (int j = 0; j < 4; ++j) hw[j] = (h[2*j] & 0xffff) | (h[2*j+1] << 16);
        *(int4*)&Apk[hiBase + off] = make_int4(hw[0], hw[1], hw[2], hw[3]);
        if (split) {
            int lw[4];
#pragma unroll
            for (int j = 0; j < 4; ++j) {
                short a = f2bf(f[2*j]   - bf2f(h[2*j]));
                short b = f2bf(f[2*j+1] - bf2f(h[2*j+1]));
                lw[j] = (a & 0xffff) | (b << 16);
            }
            *(int4*)&Apk[loBase + off] = make_int4(lw[0], lw[1], lw[2], lw[3]);
        }
    }
}

// ============ prep B-side: fp32 [K][N] -> fragment-ordered bf16 tiles (transposed) ============
__global__ __launch_bounds__(256) void prep_b(
    const float* __restrict__ W, short* __restrict__ Bpk, int K, int N, int split)
{
    const int kb = blockIdx.x, nblk = blockIdx.y, tid = threadIdx.x;
    const int kpb = K / 32;
    const int nkb = kpb << split;
    __shared__ float Ws[32][129];
    {
        const int r = tid >> 3, cbase = (tid & 7) * 4;
#pragma unroll
        for (int itc = 0; itc < 4; ++itc) {
            const int c = cbase + itc * 32;
            const float4 v = *(const float4*)&W[(size_t)(kb * 32 + r) * N + nblk * 128 + c];
            Ws[r][c] = v.x; Ws[r][c + 1] = v.y; Ws[r][c + 2] = v.z; Ws[r][c + 3] = v.w;
        }
    }
    __syncthreads();
    const size_t hiBase = ((size_t)nblk * nkb + kb) * 4096;
    const size_t loBase = hiBase + (size_t)kpb * 4096;
#pragma unroll
    for (int itr = 0; itr < 2; ++itr) {
        const int item = itr * 256 + tid;
        const int n = item >> 2, kc = item & 3;
        float f[8];
#pragma unroll
        for (int j = 0; j < 8; ++j) f[j] = Ws[kc * 8 + j][n];
        const size_t off = (size_t)(n >> 4) * 512 + (size_t)((kc << 4) | (n & 15)) * 8;
        short h[8];
#pragma unroll
        for (int j = 0; j < 8; ++j) h[j] = f2bf(f[j]);
        int hw[4];
#pragma unroll
        for (int j = 0; j < 4; ++j) hw[j] = (h[2*j] & 0xffff) | (h[2*j+1] << 16);
        *(int4*)&Bpk[hiBase + off] = make_int4(hw[0], hw[1], hw[2], hw[3]);
        if (split) {
            int lw[4];
#pragma unroll
            for (int j = 0; j < 4; ++j) {
                short a = f2bf(f[2*j]   - bf2f(h[2*j]));
                short b = f2bf(f[2*j+1] - bf2f(h[2*j+1]));
                lw[j] = (a & 0xffff) | (b << 16);
            }
            *(int4*)&Bpk[loBase + off] = make_int4(lw[0], lw[1], lw[2], lw[3]);
        }
    }
}

// ============ bf16 MFMA GEMM: counted-vmcnt deep pipeline (T3+T4 minimum form) ============
// 128x128 tile, BK=32, 4 waves. 4 LDS buffers (64KB dyn), prefetch depth 3.
// Raw s_barrier + manual vmcnt(8): tile t+1/t+2 loads stay in flight across barriers.
// Fragment-ordered tiles make every ds_read_b128 lane-linear -> no swizzle needed (T2 by construction).
// Race proof: stage(t+3) sits after 2nd barrier of iter t => all waves finished reading
// buf[(t+3)&3] == buf[(t-1)&3] (read at iter t-1). Each wave stages its own slice, so its
// own vmcnt gates its own DMA; barrier then publishes all slices.
__global__ __launch_bounds__(256) void gemm_bf16(
    const short* __restrict__ Apk, const short* __restrict__ Bpk,
    float* __restrict__ C, int N, int gx, int nkbA, int nkbB, int nkb, int split)
{
    extern __shared__ __align__(16) char smem[];   // 4 x (A 8KB | B 8KB) = 64 KB
    const int tid = threadIdx.x;
    const int lane = tid & 63, w = tid >> 6;
    const int wr = w >> 1, wc = w & 1;

    // bijective XCD swizzle (nwg % 8 == 0), bx-major
    const int nwg = gridDim.x, cpx = nwg >> 3, bid = blockIdx.x;
    const int swz = (bid & 7) * cpx + (bid >> 3);
    const int gy = nwg / gx;
    const int by = swz % gy, bx = swz / gy;
    const int bm = by * 128, bn = bx * 128;
    const size_t Abase = (size_t)by * nkbA * 4096;
    const size_t Bbase = (size_t)bx * nkbB * 4096;

    f32x4 acc[4][4];
#pragma unroll
    for (int m = 0; m < 4; ++m)
#pragma unroll
        for (int n = 0; n < 4; ++n) acc[m][n] = (f32x4){0.f, 0.f, 0.f, 0.f};

    auto stage = [&](int vkb) {
        const int bi = vkb & 3;
        int akb, bkb;
        if (split) { akb = (vkb < 64) ? vkb : vkb - 64; bkb = (vkb < 128) ? vkb : vkb - 128; }
        else       { akb = vkb; bkb = vkb; }
        const short* ga = Apk + Abase + (size_t)akb * 4096;
        const short* gb = Bpk + Bbase + (size_t)bkb * 4096;
        short* As = (short*)(smem + bi * 16384);
        short* Bs = (short*)(smem + bi * 16384 + 8192);
        gload16(ga + w * 1024,       As + w * 1024);
        gload16(ga + w * 1024 + 512, As + w * 1024 + 512);
        gload16(gb + w * 1024,       Bs + w * 1024);
        gload16(gb + w * 1024 + 512, Bs + w * 1024 + 512);
    };

    stage(0); stage(1); stage(2);                  // prologue: depth-3 prefetch
    __builtin_amdgcn_sched_barrier(0);

    for (int t = 0; t < nkb; ++t) {
        const int rem = nkb - 1 - t;
        if (rem >= 2)      asm volatile("s_waitcnt vmcnt(8)" ::: "memory");
        else if (rem == 1) asm volatile("s_waitcnt vmcnt(4)" ::: "memory");
        else               asm volatile("s_waitcnt vmcnt(0)" ::: "memory");
        __builtin_amdgcn_s_barrier();              // buf[t&3] published to all waves
        __builtin_amdgcn_sched_barrier(0);

        const short* As = (const short*)(smem + (t & 3) * 16384);
        const short* Bs = (const short*)(smem + (t & 3) * 16384 + 8192);
        short8 af[4], bfr[4];
#pragma unroll
        for (int m = 0; m < 4; ++m)
            af[m] = *(const short8*)&As[(wr * 4 + m) * 512 + lane * 8];
#pragma unroll
        for (int n = 0; n < 4; ++n)
            bfr[n] = *(const short8*)&Bs[(wc * 4 + n) * 512 + lane * 8];

        __builtin_amdgcn_s_setprio(1);
#pragma unroll
        for (int m = 0; m < 4; ++m)
#pragma unroll
            for (int n = 0; n < 4; ++n)
                acc[m][n] = __builtin_amdgcn_mfma_f32_16x16x32_bf16(af[m], bfr[n], acc[m][n], 0, 0, 0);
        __builtin_amdgcn_s_setprio(0);

        __builtin_amdgcn_s_barrier();              // all waves done reading buf[t&3]
        __builtin_amdgcn_sched_barrier(0);
        if (t + 3 < nkb) stage(t + 3);             // overwrites buf[(t-1)&3]: safe (see proof)
    }

    // ---- vectorized epilogue: bounce 32x128 fp32 chunks through LDS (stride 132), float4 stores ----
    float* Cs = (float*)smem;
    const int rq = lane >> 4, r16 = lane & 15;
#pragma unroll
    for (int m = 0; m < 4; ++m) {
        __syncthreads();
#pragma unroll
        for (int n = 0; n < 4; ++n)
#pragma unroll
            for (int j = 0; j < 4; ++j)
                Cs[(wr * 16 + rq * 4 + j) * 132 + wc * 64 + n * 16 + r16] = acc[m][n][j];
        __syncthreads();
#pragma unroll
        for (int it2 = 0; it2 < 4; ++it2) {
            const int idx = it2 * 256 + tid;
            const int lr = idx >> 5, c4 = (idx & 31) * 4;
            const int grow = bm + (lr >> 4) * 64 + m * 16 + (lr & 15);
            *(float4*)&C[(size_t)grow * N + bn + c4] = *(const float4*)&Cs[lr * 132 + c4];
        }
    }
}

// ===================== conv3 + rmsnorm + rope -> bf16 q,k (scale folded), bf16 V^T, fp32 intent ==========
__global__ __launch_bounds__(128) void conv_norm_rope(
    const float* __restrict__ qkv,
    const float* __restrict__ wq, const float* __restrict__ wk,
    const float* __restrict__ wv, const float* __restrict__ wi,
    const float* __restrict__ qnw, const float* __restrict__ knw,
    const float* __restrict__ cosT, const float* __restrict__ sinT,
    short* __restrict__ qt, short* __restrict__ kt,
    short* __restrict__ vtt, float* __restrict__ it)
{
    const int t = blockIdx.x, h = blockIdx.y, b = blockIdx.z;
    const int d = threadIdx.x;
    const int c = h * HD + d;
    const size_t rowbase = ((size_t)(b * T_SEQ + t)) * (4 * C_DIM);

    const float* Wt[4] = { wq, wk, wv, wi };
    float z[4];
#pragma unroll
    for (int s = 0; s < 4; ++s) {
        const float* w = Wt[s] + c * 3;
        float w0 = w[0], w1 = w[1], w2 = w[2];
        size_t idx = rowbase + (size_t)s * C_DIM + c;
        float x0 = qkv[idx];
        float x1 = (t >= 1) ? qkv[idx - (size_t)4 * C_DIM] : 0.f;
        float x2 = (t >= 2) ? qkv[idx - (size_t)8 * C_DIM] : 0.f;
        z[s] = fmaf(w0, x2, fmaf(w1, x1, w2 * x0));
    }

    float sq = z[0] * z[0], sk = z[1] * z[1];
#pragma unroll
    for (int off = 32; off > 0; off >>= 1) {
        sq += __shfl_down(sq, off);
        sk += __shfl_down(sk, off);
    }
    __shared__ float red[4];
    const int wid = threadIdx.x >> 6, lane = threadIdx.x & 63;
    if (lane == 0) { red[wid * 2 + 0] = sq; red[wid * 2 + 1] = sk; }
    __syncthreads();
    const float rq = rsqrtf((red[0] + red[2]) * (1.f / HD) + 1e-5f);
    const float rk = rsqrtf((red[1] + red[3]) * (1.f / HD) + 1e-5f);

    float zq = z[0] * rq * qnw[d];
    float zk = z[1] * rk * knw[d];
    float pq = __shfl_xor(zq, 1);
    float pk = __shfl_xor(zk, 1);
    float cv = cosT[t * (HD / 2) + (d >> 1)];
    float sv = sinT[t * (HD / 2) + (d >> 1)];
    float oq = (d & 1) ? (pq * sv + zq * cv) : (zq * cv - pq * sv);
    float ok = (d & 1) ? (pk * sv + zk * cv) : (zk * cv - pk * sv);
    oq *= 0.08838834764831845f;   // fold 1/sqrt(128) into q

    size_t o = ((size_t)(b * NH + h) * T_SEQ + t) * HD + d;
    qt[o] = f2bf(oq);
    kt[o] = f2bf(ok);
    vtt[((size_t)(b * NH + h) * HD + d) * T_SEQ + t] = f2bf(z[2]);   // V transposed [bh][d][t]
    it[o] = z[3];
}

// ===================== bf16 MFMA causal flash attention + sigmoid gate =====================
__global__ __launch_bounds__(256, 3) void flash_mfma(
    const short* __restrict__ qt, const short* __restrict__ kt,
    const short* __restrict__ vtt, const float* __restrict__ it,
    float* __restrict__ y)
{
    __shared__ short lds_k[8192];   // [64 key][128 d] bf16, swizzled
    __shared__ short lds_v[8192];   // [128 d][64 key] bf16, swizzled
    __shared__ short lds_p[4096];   // 4 waves x [16 row][64 key] bf16, swizzled

    const int tid = threadIdx.x;
    const int lane = tid & 63, w = tid >> 6;
    const int r16 = lane & 15, g = lane >> 4;

    const int blk = blockIdx.x;
    const int xcd = blk & 7, idx = blk >> 3;
    const int bh = xcd * 4 + (idx & 3);
    const int qt_i = 31 - (idx >> 2);
    const int b = bh >> 4, h = bh & 15;
    const int q0 = qt_i * 64;
    const int qrow = q0 + w * 16;

    char* KsB = (char*)lds_k;
    char* VsB = (char*)lds_v;
    char* PsB = (char*)lds_p + w * 2048;

    short8 qf[4];
    {
        const short* qp = qt + ((size_t)bh * T_SEQ + qrow + r16) * HD;
#pragma unroll
        for (int kc = 0; kc < 4; ++kc)
            qf[kc] = *(const short8*)(qp + kc * 32 + g * 8);
    }

    f32x4 o[8];
    float m[4], l[4];
#pragma unroll
    for (int dn = 0; dn < 8; ++dn) o[dn] = (f32x4){0.f, 0.f, 0.f, 0.f};
#pragma unroll
    for (int j = 0; j < 4; ++j) { m[j] = -1e30f; l[j] = 0.f; }

    const short* kbh = kt + (size_t)bh * T_SEQ * HD;
    const short* vbh = vtt + (size_t)bh * HD * T_SEQ;

    for (int kti = 0; kti <= qt_i; ++kti) {
        const int k0 = kti * 64;
        __syncthreads();
#pragma unroll
        for (int i = 0; i < 4; ++i) {
            const int ix = tid + i * 256;
            const int row = ix >> 4, dch = ix & 15;
            short8 v = *(const short8*)(kbh + (size_t)(k0 + row) * HD + dch * 8);
            *(short8*)(KsB + row * 256 + ((dch * 16) ^ ((row & 7) << 4))) = v;
        }
#pragma unroll
        for (int i = 0; i < 4; ++i) {
            const int ix = tid + i * 256;
            const int dr = ix >> 3, kch = ix & 7;
            short8 v = *(const short8*)(vbh + (size_t)dr * T_SEQ + k0 + kch * 8);
            *(short8*)(VsB + dr * 128 + ((kch * 16) ^ ((dr & 7) << 4))) = v;
        }
        __syncthreads();

        f32x4 sacc[4];
#pragma unroll
        for (int nt = 0; nt < 4; ++nt) sacc[nt] = (f32x4){0.f, 0.f, 0.f, 0.f};
        __builtin_amdgcn_s_setprio(1);
#pragma unroll
        for (int nt = 0; nt < 4; ++nt) {
            const int key = nt * 16 + r16;
#pragma unroll
            for (int kc = 0; kc < 4; ++kc) {
                const short8 kf = *(const short8*)(KsB + key * 256 +
                                    ((kc * 64 + g * 16) ^ ((r16 & 7) << 4)));
                sacc[nt] = __builtin_amdgcn_mfma_f32_16x16x32_bf16(qf[kc], kf, sacc[nt], 0, 0, 0);
            }
        }
        __builtin_amdgcn_s_setprio(0);

        const bool diag = (kti == qt_i);
#pragma unroll
        for (int j = 0; j < 4; ++j) {
            const int qi = qrow + g * 4 + j;
            float s0 = sacc[0][j], s1 = sacc[1][j], s2 = sacc[2][j], s3 = sacc[3][j];
            if (diag) {
                if (k0 +      r16 > qi) s0 = -1e30f;
                if (k0 + 16 + r16 > qi) s1 = -1e30f;
                if (k0 + 32 + r16 > qi) s2 = -1e30f;
                if (k0 + 48 + r16 > qi) s3 = -1e30f;
            }
            float mx = fmaxf(fmaxf(s0, s1), fmaxf(s2, s3));
            mx = fmaxf(mx, __shfl_xor(mx, 1));
            mx = fmaxf(mx, __shfl_xor(mx, 2));
            mx = fmaxf(mx, __shfl_xor(mx, 4));
            mx = fmaxf(mx, __shfl_xor(mx, 8));
            const float mn = fmaxf(m[j], mx);
            const float corr = __expf(m[j] - mn);
            m[j] = mn;
            float p0 = __expf(s0 - mn), p1 = __expf(s1 - mn);
            float p2 = __expf(s2 - mn), p3 = __expf(s3 - mn);
            float ps = p0 + p1 + p2 + p3;
            ps += __shfl_xor(ps, 1);
            ps += __shfl_xor(ps, 2);
            ps += __shfl_xor(ps, 4);
            ps += __shfl_xor(ps, 8);
            l[j] = l[j] * corr + ps;
#pragma unroll
            for (int dn = 0; dn < 8; ++dn) o[dn][j] *= corr;
            const int row = g * 4 + j;
            const int rsw = (row & 7) << 4;
            *(short*)(PsB + row * 128 + ((0  + r16 * 2) ^ rsw)) = f2bf(p0);
            *(short*)(PsB + row * 128 + ((32 + r16 * 2) ^ rsw)) = f2bf(p1);
            *(short*)(PsB + row * 128 + ((64 + r16 * 2) ^ rsw)) = f2bf(p2);
            *(short*)(PsB + row * 128 + ((96 + r16 * 2) ^ rsw)) = f2bf(p3);
        }

        short8 pf[2];
#pragma unroll
        for (int kc2 = 0; kc2 < 2; ++kc2)
            pf[kc2] = *(const short8*)(PsB + r16 * 128 +
                        ((kc2 * 64 + g * 16) ^ ((r16 & 7) << 4)));
        __builtin_amdgcn_s_setprio(1);
#pragma unroll
        for (int dn = 0; dn < 8; ++dn) {
            const int d = dn * 16 + r16;
#pragma unroll
            for (int kc2 = 0; kc2 < 2; ++kc2) {
                const short8 vf = *(const short8*)(VsB + d * 128 +
                                    ((kc2 * 64 + g * 16) ^ ((r16 & 7) << 4)));
                o[dn] = __builtin_amdgcn_mfma_f32_16x16x32_bf16(pf[kc2], vf, o[dn], 0, 0, 0);
            }
        }
        __builtin_amdgcn_s_setprio(0);
    }

#pragma unroll
    for (int j = 0; j < 4; ++j) {
        const float inv = 1.f / l[j];
        const int t = qrow + g * 4 + j;
        const float* ip = it + ((size_t)bh * T_SEQ + t) * HD;
        float* yp = y + ((size_t)(b * T_SEQ + t)) * C_DIM + h * HD;
#pragma unroll
        for (int dn = 0; dn < 8; ++dn) {
            const int d = dn * 16 + r16;
            const float gate = 1.f / (1.f + __expf(-ip[d]));
            yp[d] = o[dn][j] * inv * gate;
        }
    }
}

// ===================== launch =====================
extern "C" void kernel_launch(void* const* d_in, const int* in_sizes, int n_in,
                              void* d_out, int out_size, void* d_ws, size_t ws_size,
                              hipStream_t stream)
{
    const float* x     = (const float*)d_in[0];
    const float* cosT  = (const float*)d_in[1];
    const float* sinT  = (const float*)d_in[2];
    const float* Wqkv  = (const float*)d_in[3];
    const float* wq    = (const float*)d_in[4];
    const float* wk    = (const float*)d_in[5];
    const float* wv    = (const float*)d_in[6];
    const float* wi    = (const float*)d_in[7];
    const float* qnw   = (const float*)d_in[8];
    const float* knw   = (const float*)d_in[9];
    const float* Wproj = (const float*)d_in[10];
    float* out = (float*)d_out;

    char* ws = (char*)d_ws;
    const size_t MiB = 1048576;
    float* qkv      = (float*)(ws);
    float* y        = (float*)(ws);
    short* y_pk     = (short*)(ws + 32 * MiB);
    short* Wproj_pk = (short*)(ws + 64 * MiB);
    short* qt  = (short*)(ws + 128 * MiB);
    short* ktp = (short*)(ws + 144 * MiB);
    short* vtt = (short*)(ws + 160 * MiB);
    float* itp = (float*)(ws + 176 * MiB);
    short* x_pk     = (short*)(ws + 128 * MiB);
    short* Wqkv_pk  = (short*)(ws + 144 * MiB);

    const size_t gemm_lds = 65536;   // 4 double-buffered 16KB tile-pairs

    // ---- stage A: qkv = x @ Wqkv (bf16 MFMA, counted-vmcnt pipeline) ----
    prep_a<<<dim3(64, 32), 256, 0, stream>>>(x, x_pk, 2048, 0);
    prep_b<<<dim3(64, 64), 256, 0, stream>>>(Wqkv, Wqkv_pk, 2048, 8192, 0);
    gemm_bf16<<<dim3(2048), 256, gemm_lds, stream>>>(x_pk, Wqkv_pk, qkv, 8192, 64, 64, 64, 64, 0);

    // ---- stage B: conv + rmsnorm + rope -> bf16 q,k,V^T + fp32 intent ----
    conv_norm_rope<<<dim3(T_SEQ, NH, 2), 128, 0, stream>>>(
        qkv, wq, wk, wv, wi, qnw, knw, cosT, sinT, qt, ktp, vtt, itp);

    // ---- stage C: bf16 MFMA flash attention + sigmoid gate ----
    flash_mfma<<<dim3(32 * 32), 256, 0, stream>>>(qt, ktp, vtt, itp, y);

    // ---- stage D: out = y @ Wproj (bf16x2 3-term split) ----
    prep_a<<<dim3(64, 32), 256, 0, stream>>>(y, y_pk, 2048, 1);
    prep_b<<<dim3(64, 16), 256, 0, stream>>>(Wproj, Wproj_pk, 2048, 2048, 1);
    gemm_bf16<<<dim3(512), 256, gemm_lds, stream>>>(y_pk, Wproj_pk, out, 2048, 16, 128, 128, 192, 1);
}

// Round 6
// 515.780 us; speedup vs baseline: 7.9730x; 1.0651x over previous
//
#include <hip/hip_runtime.h>
#include <stdint.h>

#define T_SEQ 2048
#define C_DIM 2048
#define NH    16
#define HD    128

typedef __attribute__((ext_vector_type(8))) short short8;
typedef __attribute__((ext_vector_type(4))) float f32x4;

#if defined(__has_builtin)
# if __has_builtin(__builtin_amdgcn_global_load_lds)
#  define HAVE_GLL 1
# endif
#endif
#ifndef HAVE_GLL
# define HAVE_GLL 0
#endif

__device__ __forceinline__ short f2bf(float f) {
    uint32_t x = __float_as_uint(f);
    uint32_t r = (x + 0x7fffu + ((x >> 16) & 1u)) >> 16;   // RNE
    return (short)r;
}
__device__ __forceinline__ float bf2f(short s) {
    return __uint_as_float(((uint32_t)(unsigned short)s) << 16);
}

// async global->LDS, 16B/lane; LDS dst is wave-uniform base, HW adds lane*16.
__device__ __forceinline__ void gload16(const short* g, short* l) {
    const int lane = threadIdx.x & 63;
#if HAVE_GLL
    __builtin_amdgcn_global_load_lds(
        (const __attribute__((address_space(1))) void*)(g + lane * 8),
        (__attribute__((address_space(3))) void*)l, 16, 0, 0);
#else
    *(short8*)(l + lane * 8) = *(const short8*)(g + lane * 8);
#endif
}

// ============ prep A-side: fp32 [M][K] -> fragment-ordered bf16 tiles ============
// tile (mblk,kb) = 128 rows x 32 k; layout [fm=row>>4][lane=(kc<<4)|(row&15)][j=k&7]
__global__ __launch_bounds__(256) void prep_a(
    const float* __restrict__ X, short* __restrict__ Apk, int K, int split)
{
    const int kb = blockIdx.x, mblk = blockIdx.y, tid = threadIdx.x;
    const int kpb = K / 32;
    const int nkb = kpb << split;
    const size_t hiBase = ((size_t)mblk * nkb + kb) * 4096;
    const size_t loBase = hiBase + (size_t)kpb * 4096;
#pragma unroll
    for (int itr = 0; itr < 2; ++itr) {
        const int item = itr * 256 + tid;          // 0..511 = 128 rows x 4 kchunks
        const int row = item >> 2, kc = item & 3;
        const float* xp = &X[(size_t)(mblk * 128 + row) * K + kb * 32 + kc * 8];
        float4 v0 = *(const float4*)xp;
        float4 v1 = *(const float4*)(xp + 4);
        float f[8] = { v0.x, v0.y, v0.z, v0.w, v1.x, v1.y, v1.z, v1.w };
        const size_t off = (size_t)(row >> 4) * 512 + (size_t)((kc << 4) | (row & 15)) * 8;
        short h[8];
#pragma unroll
        for (int j = 0; j < 8; ++j) h[j] = f2bf(f[j]);
        int hw[4];
#pragma unroll
        for (int j = 0; j < 4; ++j) hw[j] = (h[2*j] & 0xffff) | (h[2*j+1] << 16);
        *(int4*)&Apk[hiBase + off] = make_int4(hw[0], hw[1], hw[2], hw[3]);
        if (split) {
            int lw[4];
#pragma unroll
            for (int j = 0; j < 4; ++j) {
                short a = f2bf(f[2*j]   - bf2f(h[2*j]));
                short b = f2bf(f[2*j+1] - bf2f(h[2*j+1]));
                lw[j] = (a & 0xffff) | (b << 16);
            }
            *(int4*)&Apk[loBase + off] = make_int4(lw[0], lw[1], lw[2], lw[3]);
        }
    }
}

// ============ prep B-side: fp32 [K][N] -> fragment-ordered bf16 tiles (transposed) ============
__global__ __launch_bounds__(256) void prep_b(
    const float* __restrict__ W, short* __restrict__ Bpk, int K, int N, int split)
{
    const int kb = blockIdx.x, nblk = blockIdx.y, tid = threadIdx.x;
    const int kpb = K / 32;
    const int nkb = kpb << split;
    __shared__ float Ws[32][129];
    {
        const int r = tid >> 3, cbase = (tid & 7) * 4;
#pragma unroll
        for (int itc = 0; itc < 4; ++itc) {
            const int c = cbase + itc * 32;
            const float4 v = *(const float4*)&W[(size_t)(kb * 32 + r) * N + nblk * 128 + c];
            Ws[r][c] = v.x; Ws[r][c + 1] = v.y; Ws[r][c + 2] = v.z; Ws[r][c + 3] = v.w;
        }
    }
    __syncthreads();
    const size_t hiBase = ((size_t)nblk * nkb + kb) * 4096;
    const size_t loBase = hiBase + (size_t)kpb * 4096;
#pragma unroll
    for (int itr = 0; itr < 2; ++itr) {
        const int item = itr * 256 + tid;
        const int n = item >> 2, kc = item & 3;
        float f[8];
#pragma unroll
        for (int j = 0; j < 8; ++j) f[j] = Ws[kc * 8 + j][n];
        const size_t off = (size_t)(n >> 4) * 512 + (size_t)((kc << 4) | (n & 15)) * 8;
        short h[8];
#pragma unroll
        for (int j = 0; j < 8; ++j) h[j] = f2bf(f[j]);
        int hw[4];
#pragma unroll
        for (int j = 0; j < 4; ++j) hw[j] = (h[2*j] & 0xffff) | (h[2*j+1] << 16);
        *(int4*)&Bpk[hiBase + off] = make_int4(hw[0], hw[1], hw[2], hw[3]);
        if (split) {
            int lw[4];
#pragma unroll
            for (int j = 0; j < 4; ++j) {
                short a = f2bf(f[2*j]   - bf2f(h[2*j]));
                short b = f2bf(f[2*j+1] - bf2f(h[2*j+1]));
                lw[j] = (a & 0xffff) | (b << 16);
            }
            *(int4*)&Bpk[loBase + off] = make_int4(lw[0], lw[1], lw[2], lw[3]);
        }
    }
}

// ============ bf16 MFMA GEMM, 256-row tile, 8 waves, 4-deep counted-vmcnt pipeline ============
// BM=256 (2 packed 128-row A panels), BN=128*BNP. 512 threads = 8 waves:
//   BNP=2: waves 2x4, per-wave 128x64, acc[8][4], 32 MFMA + 12 ds_read + 4 gload / step
//   BNP=1: waves 4x2, per-wave  64x64, acc[4][4], 16 MFMA + 8 ds_read + 3 gload / step
// ONE barrier + ONE counted vmcnt per K-step. Depth-4 LDS (4*(2+BNP)*8KB), stage(t+3)
// issued after barrier(t) (all waves consumed buf[(t-1)&3] == buf[(t+3)&3] => safe).
// Fragment-ordered tiles: every ds_read_b128 lane-linear, zero bank conflicts; gload dest linear.
template<int BNP>
__global__ __launch_bounds__(512, 2) void gemm_bf16_256(
    const short* __restrict__ Apk, const short* __restrict__ Bpk,
    float* __restrict__ C, int N, int gy, int nkbA, int nkbB, int nkb, int split)
{
    constexpr int NT    = 2 + BNP;        // tiles per step (A0,A1,B0[,B1])
    constexpr int STEPB = NT * 8192;      // bytes per step buffer
    constexpr int MR    = 4 * BNP;        // m-frags per wave
    constexpr int WC    = 2 * BNP;        // wave columns
    __shared__ __align__(16) char smem[4 * STEPB];   // 128 KB (BNP=2) / 96 KB (BNP=1)

    const int tid = threadIdx.x;
    const int lane = tid & 63, w = tid >> 6;
    const int r16 = lane & 15;
    const int wr = w / WC, wc = w % WC;

    // bijective XCD swizzle (nwg % 8 == 0)
    const int nwg = gridDim.x, cpx = nwg >> 3, bid = blockIdx.x;
    const int swz = (bid & 7) * cpx + (bid >> 3);
    const int by = swz % gy, bx = swz / gy;
    const int bm = by * 256, bn = bx * (BNP * 128);
    const size_t Abase = (size_t)(2 * by) * nkbA * 4096;
    const size_t Bbase = (size_t)(BNP * bx) * nkbB * 4096;

    f32x4 acc[MR][4];
#pragma unroll
    for (int m = 0; m < MR; ++m)
#pragma unroll
        for (int n = 0; n < 4; ++n) acc[m][n] = (f32x4){0.f, 0.f, 0.f, 0.f};

    auto stage = [&](int vkb) {
        const int bi = vkb & 3;
        int akb, bkb;
        if (split) { akb = (vkb < 64) ? vkb : vkb - 64; bkb = (vkb < 128) ? vkb : vkb - 128; }
        else       { akb = vkb; bkb = vkb; }
#pragma unroll
        for (int i = 0; i < NT; ++i) {
            const int o = (w * NT + i) * 1024;           // byte offset within step buffer
            const int tileIdx = o >> 13;                 // 8 KB per tile
            const int inTile = (o & 8191) >> 1;          // shorts
            const short* g = (tileIdx < 2)
                ? Apk + Abase + ((size_t)tileIdx * nkbA + akb) * 4096 + inTile
                : Bpk + Bbase + ((size_t)(tileIdx - 2) * nkbB + bkb) * 4096 + inTile;
            gload16(g, (short*)(smem + bi * STEPB + o));
        }
    };

    stage(0); stage(1); stage(2);          // depth-3 prefetch into 4-deep ring
    __builtin_amdgcn_sched_barrier(0);

    for (int t = 0; t < nkb; ++t) {
        const int rem = nkb - 1 - t;
        if (BNP == 2) {
            if (rem >= 2)      asm volatile("s_waitcnt vmcnt(8)" ::: "memory");
            else if (rem == 1) asm volatile("s_waitcnt vmcnt(4)" ::: "memory");
            else               asm volatile("s_waitcnt vmcnt(0)" ::: "memory");
        } else {
            if (rem >= 2)      asm volatile("s_waitcnt vmcnt(6)" ::: "memory");
            else if (rem == 1) asm volatile("s_waitcnt vmcnt(3)" ::: "memory");
            else               asm volatile("s_waitcnt vmcnt(0)" ::: "memory");
        }
        __builtin_amdgcn_s_barrier();      // publish buf[t&3]; proves buf[(t+3)&3] free
        __builtin_amdgcn_sched_barrier(0);

        const char* buf = smem + (t & 3) * STEPB;
        short8 af[MR], bfr[4];
#pragma unroll
        for (int n = 0; n < 4; ++n) {
            const int fn = wc * 4 + n;
            bfr[n] = *(const short8*)(buf + 16384 + (fn >> 3) * 8192 + (fn & 7) * 1024 + lane * 16);
        }
#pragma unroll
        for (int m = 0; m < MR; ++m) {
            const int fm = wr * MR + m;
            af[m] = *(const short8*)(buf + (fm >> 3) * 8192 + (fm & 7) * 1024 + lane * 16);
        }
        if (t + 3 < nkb) stage(t + 3);     // async DMA overlaps MFMA below

        __builtin_amdgcn_s_setprio(1);
#pragma unroll
        for (int m = 0; m < MR; ++m)
#pragma unroll
            for (int n = 0; n < 4; ++n)
                acc[m][n] = __builtin_amdgcn_mfma_f32_16x16x32_bf16(af[m], bfr[n], acc[m][n], 0, 0, 0);
        __builtin_amdgcn_s_setprio(0);
    }

    // ---- epilogue: per-wave private LDS bounce (stride 68), float4 coalesced stores ----
    __builtin_amdgcn_s_barrier();          // all waves out of K-loop before smem reuse
    float* Cs = (float*)(smem + w * 4352); // 16 rows x 68 f32 per wave
    const int rq = lane >> 4;
#pragma unroll
    for (int m = 0; m < MR; ++m) {
#pragma unroll
        for (int n = 0; n < 4; ++n)
#pragma unroll
            for (int j = 0; j < 4; ++j)
                Cs[(rq * 4 + j) * 68 + n * 16 + r16] = acc[m][n][j];
#pragma unroll
        for (int it2 = 0; it2 < 4; ++it2) {
            const int r = it2 * 4 + rq;
            const float4 v = *(const float4*)&Cs[r * 68 + r16 * 4];
            const int grow = bm + wr * (MR * 16) + m * 16 + r;
            *(float4*)&C[(size_t)grow * N + bn + wc * 64 + r16 * 4] = v;
        }
    }
}

// ===================== conv3 + rmsnorm + rope -> bf16 q,k (scale folded), bf16 V^T, fp32 intent ==========
__global__ __launch_bounds__(128) void conv_norm_rope(
    const float* __restrict__ qkv,
    const float* __restrict__ wq, const float* __restrict__ wk,
    const float* __restrict__ wv, const float* __restrict__ wi,
    const float* __restrict__ qnw, const float* __restrict__ knw,
    const float* __restrict__ cosT, const float* __restrict__ sinT,
    short* __restrict__ qt, short* __restrict__ kt,
    short* __restrict__ vtt, float* __restrict__ it)
{
    const int t = blockIdx.x, h = blockIdx.y, b = blockIdx.z;
    const int d = threadIdx.x;
    const int c = h * HD + d;
    const size_t rowbase = ((size_t)(b * T_SEQ + t)) * (4 * C_DIM);

    const float* Wt[4] = { wq, wk, wv, wi };
    float z[4];
#pragma unroll
    for (int s = 0; s < 4; ++s) {
        const float* w = Wt[s] + c * 3;
        float w0 = w[0], w1 = w[1], w2 = w[2];
        size_t idx = rowbase + (size_t)s * C_DIM + c;
        float x0 = qkv[idx];
        float x1 = (t >= 1) ? qkv[idx - (size_t)4 * C_DIM] : 0.f;
        float x2 = (t >= 2) ? qkv[idx - (size_t)8 * C_DIM] : 0.f;
        z[s] = fmaf(w0, x2, fmaf(w1, x1, w2 * x0));
    }

    float sq = z[0] * z[0], sk = z[1] * z[1];
#pragma unroll
    for (int off = 32; off > 0; off >>= 1) {
        sq += __shfl_down(sq, off);
        sk += __shfl_down(sk, off);
    }
    __shared__ float red[4];
    const int wid = threadIdx.x >> 6, lane = threadIdx.x & 63;
    if (lane == 0) { red[wid * 2 + 0] = sq; red[wid * 2 + 1] = sk; }
    __syncthreads();
    const float rq = rsqrtf((red[0] + red[2]) * (1.f / HD) + 1e-5f);
    const float rk = rsqrtf((red[1] + red[3]) * (1.f / HD) + 1e-5f);

    float zq = z[0] * rq * qnw[d];
    float zk = z[1] * rk * knw[d];
    float pq = __shfl_xor(zq, 1);
    float pk = __shfl_xor(zk, 1);
    float cv = cosT[t * (HD / 2) + (d >> 1)];
    float sv = sinT[t * (HD / 2) + (d >> 1)];
    float oq = (d & 1) ? (pq * sv + zq * cv) : (zq * cv - pq * sv);
    float ok = (d & 1) ? (pk * sv + zk * cv) : (zk * cv - pk * sv);
    oq *= 0.08838834764831845f;   // fold 1/sqrt(128) into q

    size_t o = ((size_t)(b * NH + h) * T_SEQ + t) * HD + d;
    qt[o] = f2bf(oq);
    kt[o] = f2bf(ok);
    vtt[((size_t)(b * NH + h) * HD + d) * T_SEQ + t] = f2bf(z[2]);   // V transposed [bh][d][t]
    it[o] = z[3];
}

// ===================== bf16 MFMA causal flash attention + sigmoid gate (unchanged) ==========
__global__ __launch_bounds__(256, 3) void flash_mfma(
    const short* __restrict__ qt, const short* __restrict__ kt,
    const short* __restrict__ vtt, const float* __restrict__ it,
    float* __restrict__ y)
{
    __shared__ short lds_k[8192];
    __shared__ short lds_v[8192];
    __shared__ short lds_p[4096];

    const int tid = threadIdx.x;
    const int lane = tid & 63, w = tid >> 6;
    const int r16 = lane & 15, g = lane >> 4;

    const int blk = blockIdx.x;
    const int xcd = blk & 7, idx = blk >> 3;
    const int bh = xcd * 4 + (idx & 3);
    const int qt_i = 31 - (idx >> 2);
    const int b = bh >> 4, h = bh & 15;
    const int q0 = qt_i * 64;
    const int qrow = q0 + w * 16;

    char* KsB = (char*)lds_k;
    char* VsB = (char*)lds_v;
    char* PsB = (char*)lds_p + w * 2048;

    short8 qf[4];
    {
        const short* qp = qt + ((size_t)bh * T_SEQ + qrow + r16) * HD;
#pragma unroll
        for (int kc = 0; kc < 4; ++kc)
            qf[kc] = *(const short8*)(qp + kc * 32 + g * 8);
    }

    f32x4 o[8];
    float m[4], l[4];
#pragma unroll
    for (int dn = 0; dn < 8; ++dn) o[dn] = (f32x4){0.f, 0.f, 0.f, 0.f};
#pragma unroll
    for (int j = 0; j < 4; ++j) { m[j] = -1e30f; l[j] = 0.f; }

    const short* kbh = kt + (size_t)bh * T_SEQ * HD;
    const short* vbh = vtt + (size_t)bh * HD * T_SEQ;

    for (int kti = 0; kti <= qt_i; ++kti) {
        const int k0 = kti * 64;
        __syncthreads();
#pragma unroll
        for (int i = 0; i < 4; ++i) {
            const int ix = tid + i * 256;
            const int row = ix >> 4, dch = ix & 15;
            short8 v = *(const short8*)(kbh + (size_t)(k0 + row) * HD + dch * 8);
            *(short8*)(KsB + row * 256 + ((dch * 16) ^ ((row & 7) << 4))) = v;
        }
#pragma unroll
        for (int i = 0; i < 4; ++i) {
            const int ix = tid + i * 256;
            const int dr = ix >> 3, kch = ix & 7;
            short8 v = *(const short8*)(vbh + (size_t)dr * T_SEQ + k0 + kch * 8);
            *(short8*)(VsB + dr * 128 + ((kch * 16) ^ ((dr & 7) << 4))) = v;
        }
        __syncthreads();

        f32x4 sacc[4];
#pragma unroll
        for (int nt = 0; nt < 4; ++nt) sacc[nt] = (f32x4){0.f, 0.f, 0.f, 0.f};
        __builtin_amdgcn_s_setprio(1);
#pragma unroll
        for (int nt = 0; nt < 4; ++nt) {
            const int key = nt * 16 + r16;
#pragma unroll
            for (int kc = 0; kc < 4; ++kc) {
                const short8 kf = *(const short8*)(KsB + key * 256 +
                                    ((kc * 64 + g * 16) ^ ((r16 & 7) << 4)));
                sacc[nt] = __builtin_amdgcn_mfma_f32_16x16x32_bf16(qf[kc], kf, sacc[nt], 0, 0, 0);
            }
        }
        __builtin_amdgcn_s_setprio(0);

        const bool diag = (kti == qt_i);
#pragma unroll
        for (int j = 0; j < 4; ++j) {
            const int qi = qrow + g * 4 + j;
            float s0 = sacc[0][j], s1 = sacc[1][j], s2 = sacc[2][j], s3 = sacc[3][j];
            if (diag) {
                if (k0 +      r16 > qi) s0 = -1e30f;
                if (k0 + 16 + r16 > qi) s1 = -1e30f;
                if (k0 + 32 + r16 > qi) s2 = -1e30f;
                if (k0 + 48 + r16 > qi) s3 = -1e30f;
            }
            float mx = fmaxf(fmaxf(s0, s1), fmaxf(s2, s3));
            mx = fmaxf(mx, __shfl_xor(mx, 1));
            mx = fmaxf(mx, __shfl_xor(mx, 2));
            mx = fmaxf(mx, __shfl_xor(mx, 4));
            mx = fmaxf(mx, __shfl_xor(mx, 8));
            const float mn = fmaxf(m[j], mx);
            const float corr = __expf(m[j] - mn);
            m[j] = mn;
            float p0 = __expf(s0 - mn), p1 = __expf(s1 - mn);
            float p2 = __expf(s2 - mn), p3 = __expf(s3 - mn);
            float ps = p0 + p1 + p2 + p3;
            ps += __shfl_xor(ps, 1);
            ps += __shfl_xor(ps, 2);
            ps += __shfl_xor(ps, 4);
            ps += __shfl_xor(ps, 8);
            l[j] = l[j] * corr + ps;
#pragma unroll
            for (int dn = 0; dn < 8; ++dn) o[dn][j] *= corr;
            const int row = g * 4 + j;
            const int rsw = (row & 7) << 4;
            *(short*)(PsB + row * 128 + ((0  + r16 * 2) ^ rsw)) = f2bf(p0);
            *(short*)(PsB + row * 128 + ((32 + r16 * 2) ^ rsw)) = f2bf(p1);
            *(short*)(PsB + row * 128 + ((64 + r16 * 2) ^ rsw)) = f2bf(p2);
            *(short*)(PsB + row * 128 + ((96 + r16 * 2) ^ rsw)) = f2bf(p3);
        }

        short8 pf[2];
#pragma unroll
        for (int kc2 = 0; kc2 < 2; ++kc2)
            pf[kc2] = *(const short8*)(PsB + r16 * 128 +
                        ((kc2 * 64 + g * 16) ^ ((r16 & 7) << 4)));
        __builtin_amdgcn_s_setprio(1);
#pragma unroll
        for (int dn = 0; dn < 8; ++dn) {
            const int d = dn * 16 + r16;
#pragma unroll
            for (int kc2 = 0; kc2 < 2; ++kc2) {
                const short8 vf = *(const short8*)(VsB + d * 128 +
                                    ((kc2 * 64 + g * 16) ^ ((r16 & 7) << 4)));
                o[dn] = __builtin_amdgcn_mfma_f32_16x16x32_bf16(pf[kc2], vf, o[dn], 0, 0, 0);
            }
        }
        __builtin_amdgcn_s_setprio(0);
    }

#pragma unroll
    for (int j = 0; j < 4; ++j) {
        const float inv = 1.f / l[j];
        const int t = qrow + g * 4 + j;
        const float* ip = it + ((size_t)bh * T_SEQ + t) * HD;
        float* yp = y + ((size_t)(b * T_SEQ + t)) * C_DIM + h * HD;
#pragma unroll
        for (int dn = 0; dn < 8; ++dn) {
            const int d = dn * 16 + r16;
            const float gate = 1.f / (1.f + __expf(-ip[d]));
            yp[d] = o[dn][j] * inv * gate;
        }
    }
}

// ===================== launch =====================
extern "C" void kernel_launch(void* const* d_in, const int* in_sizes, int n_in,
                              void* d_out, int out_size, void* d_ws, size_t ws_size,
                              hipStream_t stream)
{
    const float* x     = (const float*)d_in[0];
    const float* cosT  = (const float*)d_in[1];
    const float* sinT  = (const float*)d_in[2];
    const float* Wqkv  = (const float*)d_in[3];
    const float* wq    = (const float*)d_in[4];
    const float* wk    = (const float*)d_in[5];
    const float* wv    = (const float*)d_in[6];
    const float* wi    = (const float*)d_in[7];
    const float* qnw   = (const float*)d_in[8];
    const float* knw   = (const float*)d_in[9];
    const float* Wproj = (const float*)d_in[10];
    float* out = (float*)d_out;

    char* ws = (char*)d_ws;
    const size_t MiB = 1048576;
    float* qkv      = (float*)(ws);
    float* y        = (float*)(ws);
    short* y_pk     = (short*)(ws + 32 * MiB);
    short* Wproj_pk = (short*)(ws + 64 * MiB);
    short* qt  = (short*)(ws + 128 * MiB);
    short* ktp = (short*)(ws + 144 * MiB);
    short* vtt = (short*)(ws + 160 * MiB);
    float* itp = (float*)(ws + 176 * MiB);
    short* x_pk     = (short*)(ws + 128 * MiB);
    short* Wqkv_pk  = (short*)(ws + 144 * MiB);

    // ---- stage A: qkv = x @ Wqkv (256x256 tile, 8-wave deep pipeline) ----
    prep_a<<<dim3(64, 32), 256, 0, stream>>>(x, x_pk, 2048, 0);
    prep_b<<<dim3(64, 64), 256, 0, stream>>>(Wqkv, Wqkv_pk, 2048, 8192, 0);
    gemm_bf16_256<2><<<dim3(512), 512, 0, stream>>>(x_pk, Wqkv_pk, qkv, 8192, 16, 64, 64, 64, 0);

    // ---- stage B: conv + rmsnorm + rope -> bf16 q,k,V^T + fp32 intent ----
    conv_norm_rope<<<dim3(T_SEQ, NH, 2), 128, 0, stream>>>(
        qkv, wq, wk, wv, wi, qnw, knw, cosT, sinT, qt, ktp, vtt, itp);

    // ---- stage C: bf16 MFMA flash attention + sigmoid gate ----
    flash_mfma<<<dim3(32 * 32), 256, 0, stream>>>(qt, ktp, vtt, itp, y);

    // ---- stage D: out = y @ Wproj (256x128 tile, bf16x2 3-term split; 256 blocks = 1/CU) ----
    prep_a<<<dim3(64, 32), 256, 0, stream>>>(y, y_pk, 2048, 1);
    prep_b<<<dim3(64, 16), 256, 0, stream>>>(Wproj, Wproj_pk, 2048, 2048, 1);
    gemm_bf16_256<1><<<dim3(256), 512, 0, stream>>>(y_pk, Wproj_pk, out, 2048, 16, 128, 128, 192, 1);
}